// Round 11
// baseline (302.881 us; speedup 1.0000x reference)
//
#include <hip/hip_runtime.h>
#include <math.h>

#define B_   2
#define L_   2048
#define D_   768
#define DI_  1536
#define S_   16
#define R_   48
#define M_   (B_*L_)   // 4096 tokens
#define NC_  32        // scan chunks
#define CL_  64        // chunk length

typedef unsigned short ushortT;
typedef __attribute__((ext_vector_type(4))) float f32x4;
typedef __attribute__((ext_vector_type(8))) short short8;

#if __has_builtin(__builtin_amdgcn_exp2f)
#define EXP2F(x) __builtin_amdgcn_exp2f(x)
#define KSC_ 1.4426950408889634f
#else
#define EXP2F(x) __expf(x)
#define KSC_ 1.0f
#endif

__device__ __forceinline__ float siluf(float x) { return x / (1.f + __expf(-x)); }
__device__ __forceinline__ float softplusf(float v) {
    return (v > 20.f) ? v : __logf(1.f + __expf(v));   // HW exp/log, bf16-accurate
}

__device__ __forceinline__ ushortT f2bf(float f) {
    unsigned u = __float_as_uint(f);
    unsigned r = (u + 0x7FFFu + ((u >> 16) & 1u)) >> 16;
    return (ushortT)r;
}
__device__ __forceinline__ float bf2f(ushortT h) {
    return __uint_as_float(((unsigned)h) << 16);
}

__device__ __forceinline__ void stage16(const ushortT* g, ushortT* l) {
    __builtin_amdgcn_global_load_lds(
        (const __attribute__((address_space(1))) unsigned int*)g,
        (__attribute__((address_space(3))) unsigned int*)l, 16, 0, 0);
}

__device__ __forceinline__ void storeC(float* p, float v)   { *p = v; }
__device__ __forceinline__ void storeC(ushortT* p, float v) { *p = f2bf(v); }

// ---------------------------------------------------------------------------
// Mega-convert: 8 segments fp32 -> bf16, with optional strided zero-pad.
// ---------------------------------------------------------------------------
struct Seg { const float* src; ushortT* dst; long n; int use; int out; };
struct Segs8 { Seg s[8]; };

__global__ __launch_bounds__(256) void convert_all_k(Segs8 S)
{
    const long stride = (long)gridDim.x * 256;
    for (int si = 0; si < 8; ++si) {
        Seg sg = S.s[si];
        if (sg.out == 1) {
            for (long i = blockIdx.x * 256L + threadIdx.x; i < sg.n; i += stride)
                sg.dst[i] = f2bf(sg.src[i]);
        } else {
            for (long i = blockIdx.x * 256L + threadIdx.x; i < sg.n; i += stride) {
                int c = (int)(i % sg.out);
                long r = i / sg.out;
                sg.dst[i] = (c < sg.use) ? f2bf(sg.src[r * sg.use + c]) : (ushortT)0;
            }
        }
    }
}

// ---------------------------------------------------------------------------
// Transpose-convert: out_w fp32 [D][DI] -> bf16 [DI][D], both dirs
// ---------------------------------------------------------------------------
__global__ __launch_bounds__(256) void transconv_k(
    const float* __restrict__ of, const float* __restrict__ ob,
    ushortT* __restrict__ tf, ushortT* __restrict__ tb)
{
    const int dir = blockIdx.z;
    const float* in = dir ? ob : of;
    ushortT* outp = dir ? tb : tf;
    __shared__ ushortT tile[64][66];
    const int j0 = blockIdx.x * 64;   // DI dim
    const int i0 = blockIdx.y * 64;   // D dim
    const int tid = threadIdx.x;
    const int dd = tid & 63, qr = tid >> 6;
    #pragma unroll 4
    for (int it = 0; it < 16; ++it) {
        int r = it * 4 + qr;
        tile[r][dd] = f2bf(in[(size_t)(i0 + r) * DI_ + j0 + dd]);
    }
    __syncthreads();
    #pragma unroll 4
    for (int it = 0; it < 16; ++it) {
        int r = it * 4 + qr;
        outp[(size_t)(j0 + r) * D_ + i0 + dd] = tile[dd][r];
    }
}

// ---------------------------------------------------------------------------
// Unified MFMA GEMM: C = A @ W^T, 128x128 tile, BK=64, 4 waves,
// both-sides XOR-swizzled LDS + bijective XCD-contiguous tile remap.
// z selects pointer set (P8). EPI 0: plain ; EPI 2: softplus(acc+bias[row]).
// NMASK: skip colg>=Nreal. K % 64 == 0. Per-z grid size must be % 8 == 0.
// ---------------------------------------------------------------------------
struct P8 { const ushortT* A[8]; const ushortT* W[8]; void* C[8]; const float* bias[8]; };

template<typename OutT, int EPI, bool NMASK>
__global__ __launch_bounds__(256) void mfma64(
    P8 P, int lda, int ldw, int ldc, int K, int Nreal)
{
    __shared__ ushortT As[128 * 64];
    __shared__ ushortT Ws[128 * 64];
    const ushortT* A = P.A[blockIdx.z];
    const ushortT* W = P.W[blockIdx.z];
    OutT* C = (OutT*)P.C[blockIdx.z];
    const float* bias = P.bias[blockIdx.z];
    const int tid = threadIdx.x;
    const int lane = tid & 63, wid = tid >> 6;
    const int wr = wid >> 1, wc = wid & 1;

    // XCD-contiguous remap (T1): consecutive-tile work stays on one XCD's L2.
    const int nwg = gridDim.x * gridDim.y;        // per-z plane, % 8 == 0
    const int bid = blockIdx.y * gridDim.x + blockIdx.x;
    const int wgid = (bid & 7) * (nwg >> 3) + (bid >> 3);
    const int m0 = (wgid / gridDim.x) * 128;
    const int n0 = (wgid % gridDim.x) * 128;

    f32x4 acc[4][4];
    #pragma unroll
    for (int m = 0; m < 4; ++m)
        #pragma unroll
        for (int n = 0; n < 4; ++n)
            acc[m][n] = (f32x4){0.f, 0.f, 0.f, 0.f};

    const int kq = (lane >> 4) * 8;   // shorts within 32-wide K-sub
    const int lr = lane & 15;
    const int srow = tid >> 3;        // 0..31 per pass
    const int scolb = (tid & 7) * 16; // byte col 0..112

    for (int k0 = 0; k0 < K; k0 += 64) {
        #pragma unroll
        for (int r = 0; r < 4; ++r) {
            int row = r * 32 + srow;
            int gcolb = scolb ^ ((row & 7) << 4);       // pre-swizzled source col (bytes)
            int lofs = row * 64 + (scolb >> 1);         // linear LDS dest (shorts)
            stage16(A + (size_t)(m0 + row) * lda + k0 + (gcolb >> 1), As + lofs);
            stage16(W + (size_t)(n0 + row) * ldw + k0 + (gcolb >> 1), Ws + lofs);
        }
        __syncthreads();

        #pragma unroll
        for (int sub = 0; sub < 2; ++sub) {
            short8 afr[4], bfr[4];
            #pragma unroll
            for (int m = 0; m < 4; ++m) {
                int row = wr * 64 + m * 16 + lr;
                int cs = (sub * 32 + kq) ^ ((row & 7) << 3);   // swizzled col (shorts)
                afr[m] = *(const short8*)(As + row * 64 + cs);
            }
            #pragma unroll
            for (int n = 0; n < 4; ++n) {
                int row = wc * 64 + n * 16 + lr;
                int cs = (sub * 32 + kq) ^ ((row & 7) << 3);
                bfr[n] = *(const short8*)(Ws + row * 64 + cs);
            }
            #pragma unroll
            for (int m = 0; m < 4; ++m)
                #pragma unroll
                for (int n = 0; n < 4; ++n)
                    acc[m][n] = __builtin_amdgcn_mfma_f32_16x16x32_bf16(
                        afr[m], bfr[n], acc[m][n], 0, 0, 0);
        }
        __syncthreads();
    }

    #pragma unroll
    for (int m = 0; m < 4; ++m) {
        #pragma unroll
        for (int n = 0; n < 4; ++n) {
            int colg = n0 + wc * 64 + n * 16 + (lane & 15);
            if (NMASK && colg >= Nreal) continue;
            #pragma unroll
            for (int r = 0; r < 4; ++r) {
                int rowg = m0 + wr * 64 + m * 16 + (lane >> 4) * 4 + r;
                float v = acc[m][n][r];
                if (EPI == 2) v = softplusf(v + bias[rowg]);
                storeC(&C[(size_t)rowg * ldc + colg], v);
            }
        }
    }
}

// ---------------------------------------------------------------------------
// Reduce 4 dbc partials -> dbc fp32 [M][80] + dbc48 bf16 [M][64] (pad 0)
// ---------------------------------------------------------------------------
__global__ __launch_bounds__(256) void pack48red_k(
    const float* __restrict__ part,
    float* __restrict__ dbc_f, float* __restrict__ dbc_b,
    ushortT* __restrict__ dbc48_f, ushortT* __restrict__ dbc48_b)
{
    const long n = (long)M_ * 80;
    for (long i = blockIdx.x * 256L + threadIdx.x; i < 2 * n; i += (long)gridDim.x * 256) {
        int dir = (i >= n);
        long j = dir ? i - n : i;
        int col = (int)(j % 80);
        long m = j / 80;
        size_t base = ((size_t)dir * 4 * M_ + m) * 80 + col;
        float sum = part[base] + part[base + (size_t)M_ * 80]
                  + part[base + (size_t)2 * M_ * 80] + part[base + (size_t)3 * M_ * 80];
        (dir ? dbc_b : dbc_f)[m * 80 + col] = sum;
        if (col < 64)
            (dir ? dbc48_b : dbc48_f)[m * 64 + col] = (col < 48) ? f2bf(sum) : (ushortT)0;
    }
}

// ---------------------------------------------------------------------------
// Fused depthwise conv (K=4) + bias + SiLU, emitting BOTH layouts:
//   xcvcat [m][3072] (dir half) and xcvt [d][m]
// ---------------------------------------------------------------------------
__global__ __launch_bounds__(256) void conv_fused_k(
    const ushortT* __restrict__ xc_f, const ushortT* __restrict__ xc_b,
    const float* __restrict__ cwf, const float* __restrict__ cwb,
    const float* __restrict__ cbf, const float* __restrict__ cbb,
    ushortT* __restrict__ xcvcat,
    ushortT* __restrict__ xcvt_f, ushortT* __restrict__ xcvt_b)
{
    const int dir = blockIdx.z;
    const ushortT* xc = dir ? xc_b : xc_f;
    const float* cw = dir ? cwb : cwf;
    const float* cb = dir ? cbb : cbf;
    ushortT* xcvt = dir ? xcvt_b : xcvt_f;
    const int dirOff = dir * DI_;

    const int tid = threadIdx.x;
    const int m0 = blockIdx.x * 64;
    const int d0 = blockIdx.y * 64;
    const int b = m0 / L_;
    const int t0 = m0 % L_;
    const int dd = tid & 63;
    const int qr = tid >> 6;

    __shared__ ushortT xt[68][66];
    __shared__ ushortT ot[64][66];

    const int tbase = t0 + (dir ? 0 : -3);
    #pragma unroll 4
    for (int it = 0; it < 17; ++it) {
        int r = it * 4 + qr;
        if (r < 68) {
            int tr = tbase + r;
            ushortT v = 0;
            if (r < 67 && tr >= 0 && tr < L_)
                v = xc[((size_t)b * L_ + tr) * DI_ + d0 + dd];
            xt[r][dd] = v;
        }
    }
    __syncthreads();

    float cwv[4];
    #pragma unroll
    for (int q = 0; q < 4; ++q)
        cwv[q] = dir ? cw[(d0 + dd) * 4 + 3 - q] : cw[(d0 + dd) * 4 + q];
    const float cbv = cb[d0 + dd];

    #pragma unroll 4
    for (int it = 0; it < 16; ++it) {
        int tt = it * 4 + qr;
        float acc = cbv;
        #pragma unroll
        for (int q = 0; q < 4; ++q)
            acc += cwv[q] * bf2f(xt[tt + q][dd]);
        ushortT r16 = f2bf(siluf(acc));
        xcvcat[(size_t)(m0 + tt) * 3072 + dirOff + d0 + dd] = r16;
        ot[tt][dd] = r16;
    }
    __syncthreads();

    #pragma unroll 4
    for (int it = 0; it < 16; ++it) {
        int rr = it * 4 + qr;
        int cc = dd;
        xcvt[(size_t)(d0 + rr) * M_ + m0 + cc] = ot[cc][rr];
    }
}

// ---------------------------------------------------------------------------
// Scan: lane-pair split — thread owns 8 of the 16 states.
// ---------------------------------------------------------------------------
template<int DIR>
__device__ __forceinline__ void scan1_body(
    const ushortT* __restrict__ xcv_t, const ushortT* __restrict__ dt_t,
    const float* __restrict__ dbc, const float* __restrict__ Alog,
    float* __restrict__ aprod, float* __restrict__ hloc,
    float (*Bs)[16], int c, int b, int d, int half, int tid)
{
    const int t0 = c * CL_;
    #pragma unroll
    for (int it = 0; it < CL_ / 16; ++it) {
        int row = it * 16 + (tid >> 4);
        int col = tid & 15;
        int tau = t0 + row;
        int pos = DIR ? (L_ - 1 - tau) : tau;
        Bs[row][col] = dbc[((size_t)b * L_ + pos) * 80 + R_ + col];
    }
    __syncthreads();

    float A2[8];
    #pragma unroll
    for (int s = 0; s < 8; ++s)
        A2[s] = -__expf(Alog[d * S_ + half * 8 + s]) * KSC_;

    const size_t sbase = (size_t)d * M_ + b * L_;
    float h[8];
    #pragma unroll
    for (int s = 0; s < 8; ++s) h[s] = 0.f;
    float sdt = 0.f;

    for (int g = 0; g < CL_ / 32; ++g) {
        const int t0g = t0 + 32 * g;
        const int tb = DIR ? (L_ - 32 - t0g) : t0g;
        const ushortT* dp = dt_t + sbase + tb;
        const ushortT* xp = xcv_t + sbase + tb;
        short8 d8[4], x8[4];
        #pragma unroll
        for (int v = 0; v < 4; ++v) {
            d8[v] = *(const short8*)(dp + v * 8);
            x8[v] = *(const short8*)(xp + v * 8);
        }
        #pragma unroll
        for (int jj = 0; jj < 32; ++jj) {
            const int q = DIR ? (31 - jj) : jj;
            float dtv = bf2f((ushortT)d8[q >> 3][q & 7]);
            float xv  = bf2f((ushortT)x8[q >> 3][q & 7]);
            float bx = dtv * xv;
            sdt += dtv;
            const int row = 32 * g + jj;
            const f32x4* B4 = (const f32x4*)&Bs[row][0];
            #pragma unroll
            for (int qq = 0; qq < 2; ++qq) {
                f32x4 Bq = B4[half * 2 + qq];
                #pragma unroll
                for (int e2 = 0; e2 < 4; ++e2) {
                    int s = qq * 4 + e2;
                    float a = EXP2F(dtv * A2[s]);
                    h[s] = a * h[s] + bx * Bq[e2];
                }
            }
        }
    }
    size_t idx = ((((size_t)DIR * B_ + b) * NC_ + c) * DI_ + d) * S_ + half * 8;
    #pragma unroll
    for (int qv = 0; qv < 2; ++qv) {
        f32x4 ap, hl;
        #pragma unroll
        for (int e = 0; e < 4; ++e) {
            ap[e] = EXP2F(A2[qv * 4 + e] * sdt);
            hl[e] = h[qv * 4 + e];
        }
        *(f32x4*)(aprod + idx + qv * 4) = ap;
        *(f32x4*)(hloc  + idx + qv * 4) = hl;
    }
}

__global__ __launch_bounds__(256) void scan1_k(
    const ushortT* __restrict__ xcvt_f, const ushortT* __restrict__ dtt_f,
    const float* __restrict__ dbc_f, const float* __restrict__ Af,
    const ushortT* __restrict__ xcvt_b, const ushortT* __restrict__ dtt_b,
    const float* __restrict__ dbc_b, const float* __restrict__ Ab,
    float* __restrict__ aprod, float* __restrict__ hloc)
{
    __shared__ float Bs[CL_][16];
    const int dir = blockIdx.z / NC_, c = blockIdx.z % NC_;
    const int d = blockIdx.x * 128 + (threadIdx.x >> 1);
    const int half = threadIdx.x & 1;
    const int b = blockIdx.y;
    if (dir == 0)
        scan1_body<0>(xcvt_f, dtt_f, dbc_f, Af, aprod, hloc, Bs, c, b, d, half, threadIdx.x);
    else
        scan1_body<1>(xcvt_b, dtt_b, dbc_b, Ab, aprod, hloc, Bs, c, b, d, half, threadIdx.x);
}

__global__ __launch_bounds__(256) void scan2_k(
    float* __restrict__ aprod, const float* __restrict__ hloc)
{
    int q = blockIdx.x * 256 + threadIdx.x;
    if (q >= 2 * B_ * DI_ * S_) return;
    int s = q & 15;
    int t = q >> 4;
    int d = t % DI_;
    int t2 = t / DI_;
    int b = t2 & 1, dir = t2 >> 1;
    float h = 0.f;
    for (int c = 0; c < NC_; ++c) {
        size_t idx = ((((size_t)dir * B_ + b) * NC_ + c) * DI_ + d) * S_ + s;
        float a = aprod[idx], hl = hloc[idx];
        aprod[idx] = h;
        h = hl + a * h;
    }
}

// ---------------------------------------------------------------------------
// Scan pass 3 with FUSED GATE: recompute h with h_in, y = sum_s h*C, then
// write (y + xv*Dp) * silu(z) directly into xcvcat[m][3072].
// ---------------------------------------------------------------------------
template<int DIR>
__device__ __forceinline__ void scan3_body(
    const ushortT* __restrict__ xcv_t, const ushortT* __restrict__ dt_t,
    const float* __restrict__ dbc, const float* __restrict__ Alog,
    const ushortT* __restrict__ zp, const float* __restrict__ Dp,
    ushortT* __restrict__ xcv_out, const float* __restrict__ hin,
    float (*Bs)[16], float (*Cs)[16], int c, int b, int d, int half, int tid)
{
    const int t0 = c * CL_;
    #pragma unroll
    for (int it = 0; it < CL_ / 16; ++it) {
        int row = it * 16 + (tid >> 4);
        int col = tid & 15;
        int tau = t0 + row;
        int pos = DIR ? (L_ - 1 - tau) : tau;
        size_t base = ((size_t)b * L_ + pos) * 80 + R_;
        Bs[row][col] = dbc[base + col];
        Cs[row][col] = dbc[base + 16 + col];
    }
    __syncthreads();

    float A2[8];
    #pragma unroll
    for (int s = 0; s < 8; ++s)
        A2[s] = -__expf(Alog[d * S_ + half * 8 + s]) * KSC_;
    const float Dpv = Dp[d];

    size_t idx = ((((size_t)DIR * B_ + b) * NC_ + c) * DI_ + d) * S_ + half * 8;
    float h[8];
    #pragma unroll
    for (int qv = 0; qv < 2; ++qv) {
        f32x4 hv = *(const f32x4*)(hin + idx + qv * 4);
        h[qv * 4 + 0] = hv[0]; h[qv * 4 + 1] = hv[1];
        h[qv * 4 + 2] = hv[2]; h[qv * 4 + 3] = hv[3];
    }

    const size_t sbase = (size_t)d * M_ + b * L_;

    for (int g = 0; g < CL_ / 32; ++g) {
        const int t0g = t0 + 32 * g;
        const int tb = DIR ? (L_ - 32 - t0g) : t0g;
        const ushortT* dp = dt_t + sbase + tb;
        const ushortT* xp = xcv_t + sbase + tb;
        short8 d8[4], x8[4];
        #pragma unroll
        for (int v = 0; v < 4; ++v) {
            d8[v] = *(const short8*)(dp + v * 8);
            x8[v] = *(const short8*)(xp + v * 8);
        }
        #pragma unroll
        for (int jj = 0; jj < 32; ++jj) {
            const int q = DIR ? (31 - jj) : jj;
            float dtv = bf2f((ushortT)d8[q >> 3][q & 7]);
            float xv  = bf2f((ushortT)x8[q >> 3][q & 7]);
            float bx = dtv * xv;
            const int row = 32 * g + jj;
            const f32x4* B4 = (const f32x4*)&Bs[row][0];
            const f32x4* C4 = (const f32x4*)&Cs[row][0];
            float y = 0.f;
            #pragma unroll
            for (int qq = 0; qq < 2; ++qq) {
                f32x4 Bq = B4[half * 2 + qq];
                f32x4 Cq = C4[half * 2 + qq];
                #pragma unroll
                for (int e2 = 0; e2 < 4; ++e2) {
                    int s = qq * 4 + e2;
                    float a = EXP2F(dtv * A2[s]);
                    h[s] = a * h[s] + bx * Bq[e2];
                    y += h[s] * Cq[e2];
                }
            }
            y += __shfl_xor(y, 1);            // combine the two halves
            if (half == 0) {
                int tau = t0g + jj;
                int posw = DIR ? (L_ - 1 - tau) : tau;
                size_t rowo = (size_t)b * L_ + posw;
                float zv = bf2f(zp[rowo * DI_ + d]);
                xcv_out[rowo * 3072 + DIR * DI_ + d] =
                    f2bf((y + xv * Dpv) * siluf(zv));
            }
        }
    }
}

__global__ __launch_bounds__(256) void scan3_k(
    const ushortT* __restrict__ xcvt_f, const ushortT* __restrict__ dtt_f,
    const float* __restrict__ dbc_f, const float* __restrict__ Af,
    const ushortT* __restrict__ z_f, const float* __restrict__ Dp_f,
    const ushortT* __restrict__ xcvt_b, const ushortT* __restrict__ dtt_b,
    const float* __restrict__ dbc_b, const float* __restrict__ Ab,
    const ushortT* __restrict__ z_b, const float* __restrict__ Dp_b,
    ushortT* __restrict__ xcvcat, const float* __restrict__ hin)
{
    __shared__ float Bs[CL_][16];
    __shared__ float Cs[CL_][16];
    const int dir = blockIdx.z / NC_, c = blockIdx.z % NC_;
    const int d = blockIdx.x * 128 + (threadIdx.x >> 1);
    const int half = threadIdx.x & 1;
    const int b = blockIdx.y;
    if (dir == 0)
        scan3_body<0>(xcvt_f, dtt_f, dbc_f, Af, z_f, Dp_f, xcvcat, hin,
                      Bs, Cs, c, b, d, half, threadIdx.x);
    else
        scan3_body<1>(xcvt_b, dtt_b, dbc_b, Ab, z_b, Dp_b, xcvcat, hin,
                      Bs, Cs, c, b, d, half, threadIdx.x);
}

// ---------------------------------------------------------------------------
// h = x + acc0..acc3 + proj_b ; LayerNorm over D=768
// ---------------------------------------------------------------------------
__global__ __launch_bounds__(256) void final_ln_k(
    const float* __restrict__ x, const float* __restrict__ acc0,
    const float* __restrict__ acc1, const float* __restrict__ acc2,
    const float* __restrict__ acc3,
    const float* __restrict__ proj_b, const float* __restrict__ ln_g,
    const float* __restrict__ ln_b, float* __restrict__ out)
{
    const int row = blockIdx.x;
    const size_t base = (size_t)row * D_;
    __shared__ float hbuf[D_];
    __shared__ float wsum[4], wsum2[4];
    float s1 = 0.f, s2 = 0.f;
    for (int n = threadIdx.x; n < D_; n += 256) {
        float h = x[base + n] + acc0[base + n] + acc1[base + n]
                + acc2[base + n] + acc3[base + n] + proj_b[n];
        hbuf[n] = h;
        s1 += h; s2 += h * h;
    }
    #pragma unroll
    for (int off = 32; off; off >>= 1) {
        s1 += __shfl_down(s1, off);
        s2 += __shfl_down(s2, off);
    }
    const int wid = threadIdx.x >> 6;
    if ((threadIdx.x & 63) == 0) { wsum[wid] = s1; wsum2[wid] = s2; }
    __syncthreads();
    if (threadIdx.x == 0) {
        float t1 = wsum[0] + wsum[1] + wsum[2] + wsum[3];
        float t2 = wsum2[0] + wsum2[1] + wsum2[2] + wsum2[3];
        float mu = t1 / D_;
        wsum[0] = mu;
        wsum2[0] = t2 / D_ - mu * mu;
    }
    __syncthreads();
    const float mu = wsum[0];
    const float inv = rsqrtf(wsum2[0] + 1e-5f);
    for (int n = threadIdx.x; n < D_; n += 256) {
        out[base + n] = (hbuf[n] - mu) * inv * ln_g[n] + ln_b[n];
    }
}

// ---------------------------------------------------------------------------
extern "C" void kernel_launch(void* const* d_in, const int* in_sizes, int n_in,
                              void* d_out, int out_size, void* d_ws, size_t ws_size,
                              hipStream_t stream)
{
    const float* x        = (const float*)d_in[0];
    const float* f_in_w   = (const float*)d_in[1];
    const float* f_conv_w = (const float*)d_in[2];
    const float* f_conv_b = (const float*)d_in[3];
    const float* f_xproj  = (const float*)d_in[4];
    const float* f_dt_w   = (const float*)d_in[5];
    const float* f_dt_bv  = (const float*)d_in[6];
    const float* f_A_log  = (const float*)d_in[7];
    const float* f_Dp     = (const float*)d_in[8];
    const float* f_out_w  = (const float*)d_in[9];
    const float* b_in_w   = (const float*)d_in[10];
    const float* b_conv_w = (const float*)d_in[11];
    const float* b_conv_b = (const float*)d_in[12];
    const float* b_xproj  = (const float*)d_in[13];
    const float* b_dt_w   = (const float*)d_in[14];
    const float* b_dt_bv  = (const float*)d_in[15];
    const float* b_A_log  = (const float*)d_in[16];
    const float* b_Dp     = (const float*)d_in[17];
    const float* b_out_w  = (const float*)d_in[18];
    const float* proj_w   = (const float*)d_in[19];
    const float* proj_b   = (const float*)d_in[20];
    const float* ln_g     = (const float*)d_in[21];
    const float* ln_b     = (const float*)d_in[22];
    float* out = (float*)d_out;

    // ---- workspace layout (float units) ----
    const size_t TOKH = (size_t)M_ * DI_ / 2;
    float* p = (float*)d_ws;
    ushortT* xbf       = (ushortT*)p;  p += (size_t)M_ * D_ / 2;
    ushortT* projwbf   = (ushortT*)p;  p += (size_t)D_ * DI_ / 2;
    ushortT* inwbf_f   = (ushortT*)p;  p += (size_t)2 * DI_ * D_ / 2;   // later: Wccat [768][3072]
    ushortT* inwbf_b   = (ushortT*)p;  p += (size_t)2 * DI_ * D_ / 2;   // later: outwT f+b
    ushortT* xprojbf_f = (ushortT*)p;  p += (size_t)128 * DI_ / 2;      // 80 rows valid
    ushortT* xprojbf_b = (ushortT*)p;  p += (size_t)128 * DI_ / 2;
    ushortT* dtw_f     = (ushortT*)p;  p += (size_t)DI_ * 64 / 2;
    ushortT* dtw_b     = (ushortT*)p;  p += (size_t)DI_ * 64 / 2;
    ushortT* xc_f      = (ushortT*)p;  p += TOKH;
    ushortT* z_f       = (ushortT*)p;  p += TOKH;
    ushortT* xc_b      = (ushortT*)p;  p += TOKH;
    ushortT* z_b       = (ushortT*)p;  p += TOKH;
    ushortT* xcvcat    = (ushortT*)p;  p += (size_t)M_ * 3072 / 2;
    ushortT* xcvt_f    = (ushortT*)p;  p += TOKH;
    ushortT* xcvt_b    = (ushortT*)p;  p += TOKH;
    ushortT* dtt_f     = (ushortT*)p;  p += TOKH;
    ushortT* dtt_b     = (ushortT*)p;  p += TOKH;
    float*   dbc_f     = p;            p += (size_t)M_ * 80;
    float*   dbc_b     = p;            p += (size_t)M_ * 80;
    ushortT* dbc48_f   = (ushortT*)p;  p += (size_t)M_ * 64 / 2;
    ushortT* dbc48_b   = (ushortT*)p;  p += (size_t)M_ * 64 / 2;
    float*   aprod     = p;            p += (size_t)2 * B_ * NC_ * DI_ * S_;
    float*   hloc      = p;            p += (size_t)2 * B_ * NC_ * DI_ * S_;
    // aliases (dead-before-reuse, stream-ordered):
    ushortT* Wccat   = inwbf_f;            // [768][3072], written after in_w consumed
    ushortT* outwT_f = inwbf_b;            // [1536][768]
    ushortT* outwT_b = inwbf_b + (size_t)DI_ * D_;
    float*   dbc_part = aprod;             // [8][M][80] inside aprod region
    // split-K x4 final-GEMM partials (dead after scan3; sizes == M*D floats):
    float*   accb0  = aprod;
    float*   accb1  = hloc;
    float*   accb2  = (float*)xcvt_f;
    float*   accb3  = (float*)xcvt_b;

    dim3 blk(256);

    // ---- 1) mega-convert fp32 -> bf16 ----
    Segs8 segs;
    segs.s[0] = { x,        xbf,       (long)M_ * D_,      1, 1 };
    segs.s[1] = { proj_w,   projwbf,   (long)D_ * DI_,     1, 1 };
    segs.s[2] = { f_xproj,  xprojbf_f, (long)80 * DI_,     1, 1 };
    segs.s[3] = { b_xproj,  xprojbf_b, (long)80 * DI_,     1, 1 };
    segs.s[4] = { f_dt_w,   dtw_f,     (long)DI_ * 64,    48, 64 };
    segs.s[5] = { b_dt_w,   dtw_b,     (long)DI_ * 64,    48, 64 };
    segs.s[6] = { f_in_w,   inwbf_f,   (long)2 * DI_ * D_, 1, 1 };
    segs.s[7] = { b_in_w,   inwbf_b,   (long)2 * DI_ * D_, 1, 1 };
    convert_all_k<<<1024, blk, 0, stream>>>(segs);

    // ---- 2) xz GEMM (4 halves), BK=64 + swizzle + XCD remap ----
    P8 px = {};
    px.A[0] = px.A[1] = px.A[2] = px.A[3] = xbf;
    px.W[0] = inwbf_f; px.W[1] = inwbf_f + (size_t)DI_ * D_;
    px.W[2] = inwbf_b; px.W[3] = inwbf_b + (size_t)DI_ * D_;
    px.C[0] = xc_f; px.C[1] = z_f; px.C[2] = xc_b; px.C[3] = z_b;
    mfma64<ushortT, 0, false><<<dim3(12, 32, 4), blk, 0, stream>>>(
        px, D_, D_, DI_, D_, 0);

    // ---- 3) out_w transpose-convert (into dead inwbf_b region) ----
    transconv_k<<<dim3(24, 12, 2), blk, 0, stream>>>(f_out_w, b_out_w, outwT_f, outwT_b);

    // ---- 4) Wc = proj_slice @ out_w  -> Wccat [768][3072] (dead inwbf_f) ----
    P8 pc = {};
    pc.A[0] = projwbf;       pc.A[1] = projwbf + D_;
    pc.W[0] = outwT_f;       pc.W[1] = outwT_b;
    pc.C[0] = Wccat;         pc.C[1] = Wccat + DI_;
    mfma64<ushortT, 0, false><<<dim3(12, 6, 2), blk, 0, stream>>>(
        pc, 2 * D_, D_, 3072, D_, 0);

    // ---- 5) conv + SiLU, both layouts ----
    conv_fused_k<<<dim3(M_ / 64, DI_ / 64, 2), blk, 0, stream>>>(
        xc_f, xc_b, f_conv_w, b_conv_w, f_conv_b, b_conv_b,
        xcvcat, xcvt_f, xcvt_b);

    // ---- 6) dbc split-K GEMM (8 z-slices) -> partials ----
    P8 pd = {};
    for (int z = 0; z < 8; ++z) {
        int dir = z >> 2, ks = z & 3;
        pd.A[z] = xcvcat + dir * DI_ + ks * 384;
        pd.W[z] = (dir ? xprojbf_b : xprojbf_f) + ks * 384;
        pd.C[z] = dbc_part + (size_t)z * M_ * 80;
    }
    mfma64<float, 0, true><<<dim3(1, 32, 8), blk, 0, stream>>>(
        pd, 3072, DI_, 80, 384, 80);

    // ---- 7) reduce partials -> dbc fp32 + dbc48 bf16 ----
    pack48red_k<<<1024, blk, 0, stream>>>(dbc_part, dbc_f, dbc_b, dbc48_f, dbc48_b);

    // ---- 8) dtt[d][m] = softplus(dtw @ dbc48^T + dt_b[d]) ----
    P8 pt = {};
    pt.A[0] = dtw_f;   pt.A[1] = dtw_b;
    pt.W[0] = dbc48_f; pt.W[1] = dbc48_b;
    pt.C[0] = dtt_f;   pt.C[1] = dtt_b;
    pt.bias[0] = f_dt_bv; pt.bias[1] = b_dt_bv;
    mfma64<ushortT, 2, false><<<dim3(32, 12, 2), blk, 0, stream>>>(
        pt, 64, 64, M_, 64, 0);

    // ---- 9) chunked selective scan; scan3 fuses the gate ----
    scan1_k<<<dim3(DI_ / 128, B_, 2 * NC_), blk, 0, stream>>>(
        xcvt_f, dtt_f, dbc_f, f_A_log, xcvt_b, dtt_b, dbc_b, b_A_log, aprod, hloc);
    scan2_k<<<(2 * B_ * DI_ * S_ + 255) / 256, blk, 0, stream>>>(aprod, hloc);
    scan3_k<<<dim3(DI_ / 128, B_, 2 * NC_), blk, 0, stream>>>(
        xcvt_f, dtt_f, dbc_f, f_A_log, z_f, f_Dp,
        xcvt_b, dtt_b, dbc_b, b_A_log, z_b, b_Dp,
        xcvcat, aprod);

    // ---- 10) accb = yp_cat @ Wccat^T, split-K x4 (768 blocks = 3/CU) ----
    P8 pf = {};
    pf.A[0] = xcvcat;              pf.W[0] = Wccat;              pf.C[0] = accb0;
    pf.A[1] = xcvcat + 768;        pf.W[1] = Wccat + 768;        pf.C[1] = accb1;
    pf.A[2] = xcvcat + 2 * 768;    pf.W[2] = Wccat + 2 * 768;    pf.C[2] = accb2;
    pf.A[3] = xcvcat + 3 * 768;    pf.W[3] = Wccat + 3 * 768;    pf.C[3] = accb3;
    mfma64<float, 0, false><<<dim3(6, 32, 4), blk, 0, stream>>>(
        pf, 3072, 3072, D_, 768, 0);

    // ---- 11) residual + LayerNorm ----
    final_ln_k<<<M_, blk, 0, stream>>>(x, accb0, accb1, accb2, accb3,
                                       proj_b, ln_g, ln_b, out);
}

// Round 12
// 288.569 us; speedup vs baseline: 1.0496x; 1.0496x over previous
//
#include <hip/hip_runtime.h>
#include <math.h>

#define B_   2
#define L_   2048
#define D_   768
#define DI_  1536
#define S_   16
#define R_   48
#define M_   (B_*L_)   // 4096 tokens
#define NC_  32        // scan chunks
#define CL_  64        // chunk length

typedef unsigned short ushortT;
typedef __attribute__((ext_vector_type(4))) float f32x4;
typedef __attribute__((ext_vector_type(8))) short short8;

#if __has_builtin(__builtin_amdgcn_exp2f)
#define EXP2F(x) __builtin_amdgcn_exp2f(x)
#define KSC_ 1.4426950408889634f
#else
#define EXP2F(x) __expf(x)
#define KSC_ 1.0f
#endif

__device__ __forceinline__ float siluf(float x) { return x / (1.f + __expf(-x)); }
__device__ __forceinline__ float softplusf(float v) {
    return (v > 20.f) ? v : __logf(1.f + __expf(v));   // HW exp/log, bf16-accurate
}

__device__ __forceinline__ ushortT f2bf(float f) {
    unsigned u = __float_as_uint(f);
    unsigned r = (u + 0x7FFFu + ((u >> 16) & 1u)) >> 16;
    return (ushortT)r;
}
__device__ __forceinline__ float bf2f(ushortT h) {
    return __uint_as_float(((unsigned)h) << 16);
}

__device__ __forceinline__ void stage16(const ushortT* g, ushortT* l) {
    __builtin_amdgcn_global_load_lds(
        (const __attribute__((address_space(1))) unsigned int*)g,
        (__attribute__((address_space(3))) unsigned int*)l, 16, 0, 0);
}

__device__ __forceinline__ void storeC(float* p, float v)   { *p = v; }
__device__ __forceinline__ void storeC(ushortT* p, float v) { *p = f2bf(v); }

// ---------------------------------------------------------------------------
// Mega-convert: 8 segments fp32 -> bf16, with optional strided zero-pad.
// ---------------------------------------------------------------------------
struct Seg { const float* src; ushortT* dst; long n; int use; int out; };
struct Segs8 { Seg s[8]; };

__global__ __launch_bounds__(256) void convert_all_k(Segs8 S)
{
    const long stride = (long)gridDim.x * 256;
    for (int si = 0; si < 8; ++si) {
        Seg sg = S.s[si];
        if (sg.out == 1) {
            for (long i = blockIdx.x * 256L + threadIdx.x; i < sg.n; i += stride)
                sg.dst[i] = f2bf(sg.src[i]);
        } else {
            for (long i = blockIdx.x * 256L + threadIdx.x; i < sg.n; i += stride) {
                int c = (int)(i % sg.out);
                long r = i / sg.out;
                sg.dst[i] = (c < sg.use) ? f2bf(sg.src[r * sg.use + c]) : (ushortT)0;
            }
        }
    }
}

// ---------------------------------------------------------------------------
// Transpose-convert: out_w fp32 [D][DI] -> bf16 [DI][D], both dirs
// ---------------------------------------------------------------------------
__global__ __launch_bounds__(256) void transconv_k(
    const float* __restrict__ of, const float* __restrict__ ob,
    ushortT* __restrict__ tf, ushortT* __restrict__ tb)
{
    const int dir = blockIdx.z;
    const float* in = dir ? ob : of;
    ushortT* outp = dir ? tb : tf;
    __shared__ ushortT tile[64][66];
    const int j0 = blockIdx.x * 64;   // DI dim
    const int i0 = blockIdx.y * 64;   // D dim
    const int tid = threadIdx.x;
    const int dd = tid & 63, qr = tid >> 6;
    #pragma unroll 4
    for (int it = 0; it < 16; ++it) {
        int r = it * 4 + qr;
        tile[r][dd] = f2bf(in[(size_t)(i0 + r) * DI_ + j0 + dd]);
    }
    __syncthreads();
    #pragma unroll 4
    for (int it = 0; it < 16; ++it) {
        int r = it * 4 + qr;
        outp[(size_t)(j0 + r) * D_ + i0 + dd] = tile[dd][r];
    }
}

// ---------------------------------------------------------------------------
// Unified MFMA GEMM: C = A @ W^T, 128x128 tile, BK=64, 4 waves,
// both-sides XOR-swizzled LDS + bijective XCD-contiguous tile remap.
// z selects pointer set (P8). EPI 0: plain ; EPI 2: softplus(acc+bias[row]).
// NMASK: skip colg>=Nreal. K % 64 == 0. Per-z grid size must be % 8 == 0.
// ---------------------------------------------------------------------------
struct P8 { const ushortT* A[8]; const ushortT* W[8]; void* C[8]; const float* bias[8]; };

template<typename OutT, int EPI, bool NMASK>
__global__ __launch_bounds__(256) void mfma64(
    P8 P, int lda, int ldw, int ldc, int K, int Nreal)
{
    __shared__ ushortT As[128 * 64];
    __shared__ ushortT Ws[128 * 64];
    const ushortT* A = P.A[blockIdx.z];
    const ushortT* W = P.W[blockIdx.z];
    OutT* C = (OutT*)P.C[blockIdx.z];
    const float* bias = P.bias[blockIdx.z];
    const int tid = threadIdx.x;
    const int lane = tid & 63, wid = tid >> 6;
    const int wr = wid >> 1, wc = wid & 1;

    // XCD-contiguous remap (T1): consecutive-tile work stays on one XCD's L2.
    const int nwg = gridDim.x * gridDim.y;        // per-z plane, % 8 == 0
    const int bid = blockIdx.y * gridDim.x + blockIdx.x;
    const int wgid = (bid & 7) * (nwg >> 3) + (bid >> 3);
    const int m0 = (wgid / gridDim.x) * 128;
    const int n0 = (wgid % gridDim.x) * 128;

    f32x4 acc[4][4];
    #pragma unroll
    for (int m = 0; m < 4; ++m)
        #pragma unroll
        for (int n = 0; n < 4; ++n)
            acc[m][n] = (f32x4){0.f, 0.f, 0.f, 0.f};

    const int kq = (lane >> 4) * 8;   // shorts within 32-wide K-sub
    const int lr = lane & 15;
    const int srow = tid >> 3;        // 0..31 per pass
    const int scolb = (tid & 7) * 16; // byte col 0..112

    for (int k0 = 0; k0 < K; k0 += 64) {
        #pragma unroll
        for (int r = 0; r < 4; ++r) {
            int row = r * 32 + srow;
            int gcolb = scolb ^ ((row & 7) << 4);       // pre-swizzled source col (bytes)
            int lofs = row * 64 + (scolb >> 1);         // linear LDS dest (shorts)
            stage16(A + (size_t)(m0 + row) * lda + k0 + (gcolb >> 1), As + lofs);
            stage16(W + (size_t)(n0 + row) * ldw + k0 + (gcolb >> 1), Ws + lofs);
        }
        __syncthreads();

        #pragma unroll
        for (int sub = 0; sub < 2; ++sub) {
            short8 afr[4], bfr[4];
            #pragma unroll
            for (int m = 0; m < 4; ++m) {
                int row = wr * 64 + m * 16 + lr;
                int cs = (sub * 32 + kq) ^ ((row & 7) << 3);   // swizzled col (shorts)
                afr[m] = *(const short8*)(As + row * 64 + cs);
            }
            #pragma unroll
            for (int n = 0; n < 4; ++n) {
                int row = wc * 64 + n * 16 + lr;
                int cs = (sub * 32 + kq) ^ ((row & 7) << 3);
                bfr[n] = *(const short8*)(Ws + row * 64 + cs);
            }
            #pragma unroll
            for (int m = 0; m < 4; ++m)
                #pragma unroll
                for (int n = 0; n < 4; ++n)
                    acc[m][n] = __builtin_amdgcn_mfma_f32_16x16x32_bf16(
                        afr[m], bfr[n], acc[m][n], 0, 0, 0);
        }
        __syncthreads();
    }

    #pragma unroll
    for (int m = 0; m < 4; ++m) {
        #pragma unroll
        for (int n = 0; n < 4; ++n) {
            int colg = n0 + wc * 64 + n * 16 + (lane & 15);
            if (NMASK && colg >= Nreal) continue;
            #pragma unroll
            for (int r = 0; r < 4; ++r) {
                int rowg = m0 + wr * 64 + m * 16 + (lane >> 4) * 4 + r;
                float v = acc[m][n][r];
                if (EPI == 2) v = softplusf(v + bias[rowg]);
                storeC(&C[(size_t)rowg * ldc + colg], v);
            }
        }
    }
}

// ---------------------------------------------------------------------------
// Reduce 4 dbc partials -> dbc fp32 [M][80] + dbc48 bf16 [M][64] (pad 0)
// ---------------------------------------------------------------------------
__global__ __launch_bounds__(256) void pack48red_k(
    const float* __restrict__ part,
    float* __restrict__ dbc_f, float* __restrict__ dbc_b,
    ushortT* __restrict__ dbc48_f, ushortT* __restrict__ dbc48_b)
{
    const long n = (long)M_ * 80;
    for (long i = blockIdx.x * 256L + threadIdx.x; i < 2 * n; i += (long)gridDim.x * 256) {
        int dir = (i >= n);
        long j = dir ? i - n : i;
        int col = (int)(j % 80);
        long m = j / 80;
        size_t base = ((size_t)dir * 4 * M_ + m) * 80 + col;
        float sum = part[base] + part[base + (size_t)M_ * 80]
                  + part[base + (size_t)2 * M_ * 80] + part[base + (size_t)3 * M_ * 80];
        (dir ? dbc_b : dbc_f)[m * 80 + col] = sum;
        if (col < 64)
            (dir ? dbc48_b : dbc48_f)[m * 64 + col] = (col < 48) ? f2bf(sum) : (ushortT)0;
    }
}

// ---------------------------------------------------------------------------
// Fused depthwise conv (K=4) + bias + SiLU, emitting BOTH layouts:
//   xcvcat [m][3072] (dir half) and xcvt [d][m]
// ---------------------------------------------------------------------------
__global__ __launch_bounds__(256) void conv_fused_k(
    const ushortT* __restrict__ xc_f, const ushortT* __restrict__ xc_b,
    const float* __restrict__ cwf, const float* __restrict__ cwb,
    const float* __restrict__ cbf, const float* __restrict__ cbb,
    ushortT* __restrict__ xcvcat,
    ushortT* __restrict__ xcvt_f, ushortT* __restrict__ xcvt_b)
{
    const int dir = blockIdx.z;
    const ushortT* xc = dir ? xc_b : xc_f;
    const float* cw = dir ? cwb : cwf;
    const float* cb = dir ? cbb : cbf;
    ushortT* xcvt = dir ? xcvt_b : xcvt_f;
    const int dirOff = dir * DI_;

    const int tid = threadIdx.x;
    const int m0 = blockIdx.x * 64;
    const int d0 = blockIdx.y * 64;
    const int b = m0 / L_;
    const int t0 = m0 % L_;
    const int dd = tid & 63;
    const int qr = tid >> 6;

    __shared__ ushortT xt[68][66];
    __shared__ ushortT ot[64][66];

    const int tbase = t0 + (dir ? 0 : -3);
    #pragma unroll 4
    for (int it = 0; it < 17; ++it) {
        int r = it * 4 + qr;
        if (r < 68) {
            int tr = tbase + r;
            ushortT v = 0;
            if (r < 67 && tr >= 0 && tr < L_)
                v = xc[((size_t)b * L_ + tr) * DI_ + d0 + dd];
            xt[r][dd] = v;
        }
    }
    __syncthreads();

    float cwv[4];
    #pragma unroll
    for (int q = 0; q < 4; ++q)
        cwv[q] = dir ? cw[(d0 + dd) * 4 + 3 - q] : cw[(d0 + dd) * 4 + q];
    const float cbv = cb[d0 + dd];

    #pragma unroll 4
    for (int it = 0; it < 16; ++it) {
        int tt = it * 4 + qr;
        float acc = cbv;
        #pragma unroll
        for (int q = 0; q < 4; ++q)
            acc += cwv[q] * bf2f(xt[tt + q][dd]);
        ushortT r16 = f2bf(siluf(acc));
        xcvcat[(size_t)(m0 + tt) * 3072 + dirOff + d0 + dd] = r16;
        ot[tt][dd] = r16;
    }
    __syncthreads();

    #pragma unroll 4
    for (int it = 0; it < 16; ++it) {
        int rr = it * 4 + qr;
        int cc = dd;
        xcvt[(size_t)(d0 + rr) * M_ + m0 + cc] = ot[cc][rr];
    }
}

// ---------------------------------------------------------------------------
// Scan: lane-pair split — thread owns 8 of the 16 states.
// ---------------------------------------------------------------------------
template<int DIR>
__device__ __forceinline__ void scan1_body(
    const ushortT* __restrict__ xcv_t, const ushortT* __restrict__ dt_t,
    const float* __restrict__ dbc, const float* __restrict__ Alog,
    float* __restrict__ aprod, float* __restrict__ hloc,
    float (*Bs)[16], int c, int b, int d, int half, int tid)
{
    const int t0 = c * CL_;
    #pragma unroll
    for (int it = 0; it < CL_ / 16; ++it) {
        int row = it * 16 + (tid >> 4);
        int col = tid & 15;
        int tau = t0 + row;
        int pos = DIR ? (L_ - 1 - tau) : tau;
        Bs[row][col] = dbc[((size_t)b * L_ + pos) * 80 + R_ + col];
    }
    __syncthreads();

    float A2[8];
    #pragma unroll
    for (int s = 0; s < 8; ++s)
        A2[s] = -__expf(Alog[d * S_ + half * 8 + s]) * KSC_;

    const size_t sbase = (size_t)d * M_ + b * L_;
    float h[8];
    #pragma unroll
    for (int s = 0; s < 8; ++s) h[s] = 0.f;
    float sdt = 0.f;

    for (int g = 0; g < CL_ / 32; ++g) {
        const int t0g = t0 + 32 * g;
        const int tb = DIR ? (L_ - 32 - t0g) : t0g;
        const ushortT* dp = dt_t + sbase + tb;
        const ushortT* xp = xcv_t + sbase + tb;
        short8 d8[4], x8[4];
        #pragma unroll
        for (int v = 0; v < 4; ++v) {
            d8[v] = *(const short8*)(dp + v * 8);
            x8[v] = *(const short8*)(xp + v * 8);
        }
        #pragma unroll
        for (int jj = 0; jj < 32; ++jj) {
            const int q = DIR ? (31 - jj) : jj;
            float dtv = bf2f((ushortT)d8[q >> 3][q & 7]);
            float xv  = bf2f((ushortT)x8[q >> 3][q & 7]);
            float bx = dtv * xv;
            sdt += dtv;
            const int row = 32 * g + jj;
            const f32x4* B4 = (const f32x4*)&Bs[row][0];
            #pragma unroll
            for (int qq = 0; qq < 2; ++qq) {
                f32x4 Bq = B4[half * 2 + qq];
                #pragma unroll
                for (int e2 = 0; e2 < 4; ++e2) {
                    int s = qq * 4 + e2;
                    float a = EXP2F(dtv * A2[s]);
                    h[s] = a * h[s] + bx * Bq[e2];
                }
            }
        }
    }
    size_t idx = ((((size_t)DIR * B_ + b) * NC_ + c) * DI_ + d) * S_ + half * 8;
    #pragma unroll
    for (int qv = 0; qv < 2; ++qv) {
        f32x4 ap, hl;
        #pragma unroll
        for (int e = 0; e < 4; ++e) {
            ap[e] = EXP2F(A2[qv * 4 + e] * sdt);
            hl[e] = h[qv * 4 + e];
        }
        *(f32x4*)(aprod + idx + qv * 4) = ap;
        *(f32x4*)(hloc  + idx + qv * 4) = hl;
    }
}

__global__ __launch_bounds__(256) void scan1_k(
    const ushortT* __restrict__ xcvt_f, const ushortT* __restrict__ dtt_f,
    const float* __restrict__ dbc_f, const float* __restrict__ Af,
    const ushortT* __restrict__ xcvt_b, const ushortT* __restrict__ dtt_b,
    const float* __restrict__ dbc_b, const float* __restrict__ Ab,
    float* __restrict__ aprod, float* __restrict__ hloc)
{
    __shared__ float Bs[CL_][16];
    const int dir = blockIdx.z / NC_, c = blockIdx.z % NC_;
    const int d = blockIdx.x * 128 + (threadIdx.x >> 1);
    const int half = threadIdx.x & 1;
    const int b = blockIdx.y;
    if (dir == 0)
        scan1_body<0>(xcvt_f, dtt_f, dbc_f, Af, aprod, hloc, Bs, c, b, d, half, threadIdx.x);
    else
        scan1_body<1>(xcvt_b, dtt_b, dbc_b, Ab, aprod, hloc, Bs, c, b, d, half, threadIdx.x);
}

__global__ __launch_bounds__(256) void scan2_k(
    float* __restrict__ aprod, const float* __restrict__ hloc)
{
    int q = blockIdx.x * 256 + threadIdx.x;
    if (q >= 2 * B_ * DI_ * S_) return;
    int s = q & 15;
    int t = q >> 4;
    int d = t % DI_;
    int t2 = t / DI_;
    int b = t2 & 1, dir = t2 >> 1;
    float h = 0.f;
    for (int c = 0; c < NC_; ++c) {
        size_t idx = ((((size_t)dir * B_ + b) * NC_ + c) * DI_ + d) * S_ + s;
        float a = aprod[idx], hl = hloc[idx];
        aprod[idx] = h;
        h = hl + a * h;
    }
}

// ---------------------------------------------------------------------------
// Scan pass 3: recompute with h_in, emit raw y to y_t [d][m] bf16 (packed
// 8B stores — [d][m] keeps consecutive t contiguous; gate runs separately).
// ---------------------------------------------------------------------------
template<int DIR>
__device__ __forceinline__ void scan3_body(
    const ushortT* __restrict__ xcv_t, const ushortT* __restrict__ dt_t,
    const float* __restrict__ dbc, const float* __restrict__ Alog,
    ushortT* __restrict__ y_t, const float* __restrict__ hin,
    float (*Bs)[16], float (*Cs)[16], int c, int b, int d, int half, int tid)
{
    const int t0 = c * CL_;
    #pragma unroll
    for (int it = 0; it < CL_ / 16; ++it) {
        int row = it * 16 + (tid >> 4);
        int col = tid & 15;
        int tau = t0 + row;
        int pos = DIR ? (L_ - 1 - tau) : tau;
        size_t base = ((size_t)b * L_ + pos) * 80 + R_;
        Bs[row][col] = dbc[base + col];
        Cs[row][col] = dbc[base + 16 + col];
    }
    __syncthreads();

    float A2[8];
    #pragma unroll
    for (int s = 0; s < 8; ++s)
        A2[s] = -__expf(Alog[d * S_ + half * 8 + s]) * KSC_;

    size_t idx = ((((size_t)DIR * B_ + b) * NC_ + c) * DI_ + d) * S_ + half * 8;
    float h[8];
    #pragma unroll
    for (int qv = 0; qv < 2; ++qv) {
        f32x4 hv = *(const f32x4*)(hin + idx + qv * 4);
        h[qv * 4 + 0] = hv[0]; h[qv * 4 + 1] = hv[1];
        h[qv * 4 + 2] = hv[2]; h[qv * 4 + 3] = hv[3];
    }

    const size_t sbase = (size_t)d * M_ + b * L_;
    union { ushortT u[4]; unsigned long long v; } pk;

    for (int g = 0; g < CL_ / 32; ++g) {
        const int t0g = t0 + 32 * g;
        const int tb = DIR ? (L_ - 32 - t0g) : t0g;
        const ushortT* dp = dt_t + sbase + tb;
        const ushortT* xp = xcv_t + sbase + tb;
        short8 d8[4], x8[4];
        #pragma unroll
        for (int v = 0; v < 4; ++v) {
            d8[v] = *(const short8*)(dp + v * 8);
            x8[v] = *(const short8*)(xp + v * 8);
        }
        #pragma unroll
        for (int jj = 0; jj < 32; ++jj) {
            const int q = DIR ? (31 - jj) : jj;
            float dtv = bf2f((ushortT)d8[q >> 3][q & 7]);
            float xv  = bf2f((ushortT)x8[q >> 3][q & 7]);
            float bx = dtv * xv;
            const int row = 32 * g + jj;
            const f32x4* B4 = (const f32x4*)&Bs[row][0];
            const f32x4* C4 = (const f32x4*)&Cs[row][0];
            float y = 0.f;
            #pragma unroll
            for (int qq = 0; qq < 2; ++qq) {
                f32x4 Bq = B4[half * 2 + qq];
                f32x4 Cq = C4[half * 2 + qq];
                #pragma unroll
                for (int e2 = 0; e2 < 4; ++e2) {
                    int s = qq * 4 + e2;
                    float a = EXP2F(dtv * A2[s]);
                    h[s] = a * h[s] + bx * Bq[e2];
                    y += h[s] * Cq[e2];
                }
            }
            y += __shfl_xor(y, 1);            // combine the two halves
            pk.u[DIR ? (3 - (jj & 3)) : (jj & 3)] = f2bf(y);
            if ((jj & 3) == 3 && half == 0) {
                int tst = DIR ? (L_ - 1 - t0g - jj) : (t0g + jj - 3);
                *(unsigned long long*)(y_t + sbase + tst) = pk.v;
            }
        }
    }
}

__global__ __launch_bounds__(256) void scan3_k(
    const ushortT* __restrict__ xcvt_f, const ushortT* __restrict__ dtt_f,
    const float* __restrict__ dbc_f, const float* __restrict__ Af, ushortT* __restrict__ yt_f,
    const ushortT* __restrict__ xcvt_b, const ushortT* __restrict__ dtt_b,
    const float* __restrict__ dbc_b, const float* __restrict__ Ab, ushortT* __restrict__ yt_b,
    const float* __restrict__ hin)
{
    __shared__ float Bs[CL_][16];
    __shared__ float Cs[CL_][16];
    const int dir = blockIdx.z / NC_, c = blockIdx.z % NC_;
    const int d = blockIdx.x * 128 + (threadIdx.x >> 1);
    const int half = threadIdx.x & 1;
    const int b = blockIdx.y;
    if (dir == 0)
        scan3_body<0>(xcvt_f, dtt_f, dbc_f, Af, yt_f, hin, Bs, Cs, c, b, d, half, threadIdx.x);
    else
        scan3_body<1>(xcvt_b, dtt_b, dbc_b, Ab, yt_b, hin, Bs, Cs, c, b, d, half, threadIdx.x);
}

// ---------------------------------------------------------------------------
// Gate: yp = (y + xv*Dp)*silu(z) written into xcvcat (stride 3072) in place.
// ---------------------------------------------------------------------------
__global__ __launch_bounds__(256) void gate_k(
    const ushortT* __restrict__ y_t_f, const ushortT* __restrict__ y_t_b,
    ushortT* __restrict__ xcvcat,
    const ushortT* __restrict__ z_f, const ushortT* __restrict__ z_b,
    const float* __restrict__ Dp_f, const float* __restrict__ Dp_b)
{
    const int dir = blockIdx.z;
    const ushortT* y_t = dir ? y_t_b : y_t_f;
    const ushortT* z = dir ? z_b : z_f;
    const float* Dp = dir ? Dp_b : Dp_f;
    const int dirOff = dir * DI_;
    const int tid = threadIdx.x;
    const int m0 = blockIdx.x * 64;
    const int d0 = blockIdx.y * 64;
    const int dd = tid & 63;
    const int qr = tid >> 6;
    __shared__ ushortT ys[64][66];
    #pragma unroll 4
    for (int it = 0; it < 16; ++it) {
        int r = it * 4 + qr;
        ys[r][dd] = y_t[(size_t)(d0 + r) * M_ + m0 + dd];
    }
    __syncthreads();
    const float Dpv = Dp[d0 + dd];
    #pragma unroll 4
    for (int it = 0; it < 16; ++it) {
        int mi = it * 4 + qr;
        size_t zi = (size_t)(m0 + mi) * DI_ + d0 + dd;
        size_t xi = (size_t)(m0 + mi) * 3072 + dirOff + d0 + dd;
        float yv = bf2f(ys[dd][mi]);
        float xv = bf2f(xcvcat[xi]);
        float zv = bf2f(z[zi]);
        xcvcat[xi] = f2bf((yv + xv * Dpv) * siluf(zv));
    }
}

// ---------------------------------------------------------------------------
// h = x + acc0..acc3 + proj_b ; LayerNorm over D=768
// ---------------------------------------------------------------------------
__global__ __launch_bounds__(256) void final_ln_k(
    const float* __restrict__ x, const float* __restrict__ acc0,
    const float* __restrict__ acc1, const float* __restrict__ acc2,
    const float* __restrict__ acc3,
    const float* __restrict__ proj_b, const float* __restrict__ ln_g,
    const float* __restrict__ ln_b, float* __restrict__ out)
{
    const int row = blockIdx.x;
    const size_t base = (size_t)row * D_;
    __shared__ float hbuf[D_];
    __shared__ float wsum[4], wsum2[4];
    float s1 = 0.f, s2 = 0.f;
    for (int n = threadIdx.x; n < D_; n += 256) {
        float h = x[base + n] + acc0[base + n] + acc1[base + n]
                + acc2[base + n] + acc3[base + n] + proj_b[n];
        hbuf[n] = h;
        s1 += h; s2 += h * h;
    }
    #pragma unroll
    for (int off = 32; off; off >>= 1) {
        s1 += __shfl_down(s1, off);
        s2 += __shfl_down(s2, off);
    }
    const int wid = threadIdx.x >> 6;
    if ((threadIdx.x & 63) == 0) { wsum[wid] = s1; wsum2[wid] = s2; }
    __syncthreads();
    if (threadIdx.x == 0) {
        float t1 = wsum[0] + wsum[1] + wsum[2] + wsum[3];
        float t2 = wsum2[0] + wsum2[1] + wsum2[2] + wsum2[3];
        float mu = t1 / D_;
        wsum[0] = mu;
        wsum2[0] = t2 / D_ - mu * mu;
    }
    __syncthreads();
    const float mu = wsum[0];
    const float inv = rsqrtf(wsum2[0] + 1e-5f);
    for (int n = threadIdx.x; n < D_; n += 256) {
        out[base + n] = (hbuf[n] - mu) * inv * ln_g[n] + ln_b[n];
    }
}

// ---------------------------------------------------------------------------
extern "C" void kernel_launch(void* const* d_in, const int* in_sizes, int n_in,
                              void* d_out, int out_size, void* d_ws, size_t ws_size,
                              hipStream_t stream)
{
    const float* x        = (const float*)d_in[0];
    const float* f_in_w   = (const float*)d_in[1];
    const float* f_conv_w = (const float*)d_in[2];
    const float* f_conv_b = (const float*)d_in[3];
    const float* f_xproj  = (const float*)d_in[4];
    const float* f_dt_w   = (const float*)d_in[5];
    const float* f_dt_bv  = (const float*)d_in[6];
    const float* f_A_log  = (const float*)d_in[7];
    const float* f_Dp     = (const float*)d_in[8];
    const float* f_out_w  = (const float*)d_in[9];
    const float* b_in_w   = (const float*)d_in[10];
    const float* b_conv_w = (const float*)d_in[11];
    const float* b_conv_b = (const float*)d_in[12];
    const float* b_xproj  = (const float*)d_in[13];
    const float* b_dt_w   = (const float*)d_in[14];
    const float* b_dt_bv  = (const float*)d_in[15];
    const float* b_A_log  = (const float*)d_in[16];
    const float* b_Dp     = (const float*)d_in[17];
    const float* b_out_w  = (const float*)d_in[18];
    const float* proj_w   = (const float*)d_in[19];
    const float* proj_b   = (const float*)d_in[20];
    const float* ln_g     = (const float*)d_in[21];
    const float* ln_b     = (const float*)d_in[22];
    float* out = (float*)d_out;

    // ---- workspace layout (float units) ----
    const size_t TOKH = (size_t)M_ * DI_ / 2;
    float* p = (float*)d_ws;
    ushortT* xbf       = (ushortT*)p;  p += (size_t)M_ * D_ / 2;
    ushortT* projwbf   = (ushortT*)p;  p += (size_t)D_ * DI_ / 2;
    ushortT* inwbf_f   = (ushortT*)p;  p += (size_t)2 * DI_ * D_ / 2;   // later: Wccat [768][3072]
    ushortT* inwbf_b   = (ushortT*)p;  p += (size_t)2 * DI_ * D_ / 2;   // later: outwT f+b
    ushortT* xprojbf_f = (ushortT*)p;  p += (size_t)128 * DI_ / 2;      // 80 rows valid
    ushortT* xprojbf_b = (ushortT*)p;  p += (size_t)128 * DI_ / 2;
    ushortT* dtw_f     = (ushortT*)p;  p += (size_t)DI_ * 64 / 2;
    ushortT* dtw_b     = (ushortT*)p;  p += (size_t)DI_ * 64 / 2;
    ushortT* xc_f      = (ushortT*)p;  p += TOKH;
    ushortT* z_f       = (ushortT*)p;  p += TOKH;
    ushortT* xc_b      = (ushortT*)p;  p += TOKH;
    ushortT* z_b       = (ushortT*)p;  p += TOKH;
    ushortT* xcvcat    = (ushortT*)p;  p += (size_t)M_ * 3072 / 2;
    ushortT* xcvt_f    = (ushortT*)p;  p += TOKH;
    ushortT* xcvt_b    = (ushortT*)p;  p += TOKH;
    ushortT* dtt_f     = (ushortT*)p;  p += TOKH;
    ushortT* dtt_b     = (ushortT*)p;  p += TOKH;
    float*   dbc_f     = p;            p += (size_t)M_ * 80;
    float*   dbc_b     = p;            p += (size_t)M_ * 80;
    ushortT* dbc48_f   = (ushortT*)p;  p += (size_t)M_ * 64 / 2;
    ushortT* dbc48_b   = (ushortT*)p;  p += (size_t)M_ * 64 / 2;
    float*   aprod     = p;            p += (size_t)2 * B_ * NC_ * DI_ * S_;
    float*   hloc      = p;            p += (size_t)2 * B_ * NC_ * DI_ * S_;
    // aliases (dead-before-reuse, stream-ordered):
    ushortT* Wccat   = inwbf_f;            // [768][3072], written after in_w consumed
    ushortT* outwT_f = inwbf_b;            // [1536][768]
    ushortT* outwT_b = inwbf_b + (size_t)DI_ * D_;
    float*   dbc_part = aprod;             // [8][M][80] inside aprod region
    ushortT* yt_f   = xc_f;                // xc dead after conv
    ushortT* yt_b   = xc_b;
    // split-K x4 final-GEMM partials (dead after scan3; sizes == M*D floats):
    float*   accb0  = aprod;
    float*   accb1  = hloc;
    float*   accb2  = (float*)xcvt_f;
    float*   accb3  = (float*)xcvt_b;

    dim3 blk(256);

    // ---- 1) mega-convert fp32 -> bf16 ----
    Segs8 segs;
    segs.s[0] = { x,        xbf,       (long)M_ * D_,      1, 1 };
    segs.s[1] = { proj_w,   projwbf,   (long)D_ * DI_,     1, 1 };
    segs.s[2] = { f_xproj,  xprojbf_f, (long)80 * DI_,     1, 1 };
    segs.s[3] = { b_xproj,  xprojbf_b, (long)80 * DI_,     1, 1 };
    segs.s[4] = { f_dt_w,   dtw_f,     (long)DI_ * 64,    48, 64 };
    segs.s[5] = { b_dt_w,   dtw_b,     (long)DI_ * 64,    48, 64 };
    segs.s[6] = { f_in_w,   inwbf_f,   (long)2 * DI_ * D_, 1, 1 };
    segs.s[7] = { b_in_w,   inwbf_b,   (long)2 * DI_ * D_, 1, 1 };
    convert_all_k<<<1024, blk, 0, stream>>>(segs);

    // ---- 2) xz GEMM (4 halves), BK=64 + swizzle + XCD remap ----
    P8 px = {};
    px.A[0] = px.A[1] = px.A[2] = px.A[3] = xbf;
    px.W[0] = inwbf_f; px.W[1] = inwbf_f + (size_t)DI_ * D_;
    px.W[2] = inwbf_b; px.W[3] = inwbf_b + (size_t)DI_ * D_;
    px.C[0] = xc_f; px.C[1] = z_f; px.C[2] = xc_b; px.C[3] = z_b;
    mfma64<ushortT, 0, false><<<dim3(12, 32, 4), blk, 0, stream>>>(
        px, D_, D_, DI_, D_, 0);

    // ---- 3) out_w transpose-convert (into dead inwbf_b region) ----
    transconv_k<<<dim3(24, 12, 2), blk, 0, stream>>>(f_out_w, b_out_w, outwT_f, outwT_b);

    // ---- 4) Wc = proj_slice @ out_w  -> Wccat [768][3072] (dead inwbf_f) ----
    P8 pc = {};
    pc.A[0] = projwbf;       pc.A[1] = projwbf + D_;
    pc.W[0] = outwT_f;       pc.W[1] = outwT_b;
    pc.C[0] = Wccat;         pc.C[1] = Wccat + DI_;
    mfma64<ushortT, 0, false><<<dim3(12, 6, 2), blk, 0, stream>>>(
        pc, 2 * D_, D_, 3072, D_, 0);

    // ---- 5) conv + SiLU, both layouts ----
    conv_fused_k<<<dim3(M_ / 64, DI_ / 64, 2), blk, 0, stream>>>(
        xc_f, xc_b, f_conv_w, b_conv_w, f_conv_b, b_conv_b,
        xcvcat, xcvt_f, xcvt_b);

    // ---- 6) dbc split-K GEMM (8 z-slices) -> partials ----
    P8 pd = {};
    for (int z = 0; z < 8; ++z) {
        int dir = z >> 2, ks = z & 3;
        pd.A[z] = xcvcat + dir * DI_ + ks * 384;
        pd.W[z] = (dir ? xprojbf_b : xprojbf_f) + ks * 384;
        pd.C[z] = dbc_part + (size_t)z * M_ * 80;
    }
    mfma64<float, 0, true><<<dim3(1, 32, 8), blk, 0, stream>>>(
        pd, 3072, DI_, 80, 384, 80);

    // ---- 7) reduce partials -> dbc fp32 + dbc48 bf16 ----
    pack48red_k<<<1024, blk, 0, stream>>>(dbc_part, dbc_f, dbc_b, dbc48_f, dbc48_b);

    // ---- 8) dtt[d][m] = softplus(dtw @ dbc48^T + dt_b[d]) ----
    P8 pt = {};
    pt.A[0] = dtw_f;   pt.A[1] = dtw_b;
    pt.W[0] = dbc48_f; pt.W[1] = dbc48_b;
    pt.C[0] = dtt_f;   pt.C[1] = dtt_b;
    pt.bias[0] = f_dt_bv; pt.bias[1] = b_dt_bv;
    mfma64<ushortT, 2, false><<<dim3(32, 12, 2), blk, 0, stream>>>(
        pt, 64, 64, M_, 64, 0);

    // ---- 9) chunked selective scan ----
    scan1_k<<<dim3(DI_ / 128, B_, 2 * NC_), blk, 0, stream>>>(
        xcvt_f, dtt_f, dbc_f, f_A_log, xcvt_b, dtt_b, dbc_b, b_A_log, aprod, hloc);
    scan2_k<<<(2 * B_ * DI_ * S_ + 255) / 256, blk, 0, stream>>>(aprod, hloc);
    scan3_k<<<dim3(DI_ / 128, B_, 2 * NC_), blk, 0, stream>>>(
        xcvt_f, dtt_f, dbc_f, f_A_log, yt_f,
        xcvt_b, dtt_b, dbc_b, b_A_log, yt_b, aprod);

    // ---- 10) gate (in place over xcvcat) ----
    gate_k<<<dim3(M_ / 64, DI_ / 64, 2), blk, 0, stream>>>(
        yt_f, yt_b, xcvcat, z_f, z_b, f_Dp, b_Dp);

    // ---- 11) accb = yp_cat @ Wccat^T, split-K x4 (768 blocks = 3/CU) ----
    P8 pf = {};
    pf.A[0] = xcvcat;              pf.W[0] = Wccat;              pf.C[0] = accb0;
    pf.A[1] = xcvcat + 768;        pf.W[1] = Wccat + 768;        pf.C[1] = accb1;
    pf.A[2] = xcvcat + 2 * 768;    pf.W[2] = Wccat + 2 * 768;    pf.C[2] = accb2;
    pf.A[3] = xcvcat + 3 * 768;    pf.W[3] = Wccat + 3 * 768;    pf.C[3] = accb3;
    mfma64<float, 0, false><<<dim3(6, 32, 4), blk, 0, stream>>>(
        pf, 3072, 3072, D_, 768, 0);

    // ---- 12) residual + LayerNorm ----
    final_ln_k<<<M_, blk, 0, stream>>>(x, accb0, accb1, accb2, accb3,
                                       proj_b, ln_g, ln_b, out);
}

// Round 13
// 267.832 us; speedup vs baseline: 1.1309x; 1.0774x over previous
//
#include <hip/hip_runtime.h>
#include <math.h>

#define B_   2
#define L_   2048
#define D_   768
#define DI_  1536
#define S_   16
#define R_   48
#define M_   (B_*L_)   // 4096 tokens
#define NC_  32        // scan chunks
#define CL_  64        // chunk length

typedef unsigned short ushortT;
typedef __attribute__((ext_vector_type(4))) float f32x4;
typedef __attribute__((ext_vector_type(8))) short short8;

#if __has_builtin(__builtin_amdgcn_exp2f)
#define EXP2F(x) __builtin_amdgcn_exp2f(x)
#define KSC_ 1.4426950408889634f
#else
#define EXP2F(x) __expf(x)
#define KSC_ 1.0f
#endif

__device__ __forceinline__ float siluf(float x) { return x / (1.f + __expf(-x)); }
__device__ __forceinline__ float softplusf(float v) {
    return (v > 20.f) ? v : __logf(1.f + __expf(v));
}

__device__ __forceinline__ ushortT f2bf(float f) {
    unsigned u = __float_as_uint(f);
    unsigned r = (u + 0x7FFFu + ((u >> 16) & 1u)) >> 16;
    return (ushortT)r;
}
__device__ __forceinline__ float bf2f(ushortT h) {
    return __uint_as_float(((unsigned)h) << 16);
}

__device__ __forceinline__ void stage16(const ushortT* g, ushortT* l) {
    __builtin_amdgcn_global_load_lds(
        (const __attribute__((address_space(1))) unsigned int*)g,
        (__attribute__((address_space(3))) unsigned int*)l, 16, 0, 0);
}

__device__ __forceinline__ void storeC(float* p, float v)   { *p = v; }
__device__ __forceinline__ void storeC(ushortT* p, float v) { *p = f2bf(v); }

// ---------------------------------------------------------------------------
// Mega-convert: 8 segments fp32 -> bf16, with optional strided zero-pad.
// ---------------------------------------------------------------------------
struct Seg { const float* src; ushortT* dst; long n; int use; int out; };
struct Segs8 { Seg s[8]; };

__global__ __launch_bounds__(256) void convert_all_k(Segs8 S)
{
    const long stride = (long)gridDim.x * 256;
    for (int si = 0; si < 8; ++si) {
        Seg sg = S.s[si];
        if (sg.out == 1) {
            for (long i = blockIdx.x * 256L + threadIdx.x; i < sg.n; i += stride)
                sg.dst[i] = f2bf(sg.src[i]);
        } else {
            for (long i = blockIdx.x * 256L + threadIdx.x; i < sg.n; i += stride) {
                int c = (int)(i % sg.out);
                long r = i / sg.out;
                sg.dst[i] = (c < sg.use) ? f2bf(sg.src[r * sg.use + c]) : (ushortT)0;
            }
        }
    }
}

// ---------------------------------------------------------------------------
// Transpose-convert: out_w fp32 [D][DI] -> bf16 [DI][D], both dirs
// ---------------------------------------------------------------------------
__global__ __launch_bounds__(256) void transconv_k(
    const float* __restrict__ of, const float* __restrict__ ob,
    ushortT* __restrict__ tf, ushortT* __restrict__ tb)
{
    const int dir = blockIdx.z;
    const float* in = dir ? ob : of;
    ushortT* outp = dir ? tb : tf;
    __shared__ ushortT tile[64][66];
    const int j0 = blockIdx.x * 64;   // DI dim
    const int i0 = blockIdx.y * 64;   // D dim
    const int tid = threadIdx.x;
    const int dd = tid & 63, qr = tid >> 6;
    #pragma unroll 4
    for (int it = 0; it < 16; ++it) {
        int r = it * 4 + qr;
        tile[r][dd] = f2bf(in[(size_t)(i0 + r) * DI_ + j0 + dd]);
    }
    __syncthreads();
    #pragma unroll 4
    for (int it = 0; it < 16; ++it) {
        int r = it * 4 + qr;
        outp[(size_t)(j0 + r) * D_ + i0 + dd] = tile[dd][r];
    }
}

// ---------------------------------------------------------------------------
// Unified MFMA GEMM: C = A @ W^T, 128x128 tile, BK=64, 4 waves,
// both-sides XOR-swizzled LDS + bijective XCD-contiguous tile remap.
// ---------------------------------------------------------------------------
struct P8 { const ushortT* A[8]; const ushortT* W[8]; void* C[8]; const float* bias[8]; };

template<typename OutT, int EPI, bool NMASK>
__global__ __launch_bounds__(256) void mfma64(
    P8 P, int lda, int ldw, int ldc, int K, int Nreal)
{
    __shared__ ushortT As[128 * 64];
    __shared__ ushortT Ws[128 * 64];
    const ushortT* A = P.A[blockIdx.z];
    const ushortT* W = P.W[blockIdx.z];
    OutT* C = (OutT*)P.C[blockIdx.z];
    const float* bias = P.bias[blockIdx.z];
    const int tid = threadIdx.x;
    const int lane = tid & 63, wid = tid >> 6;
    const int wr = wid >> 1, wc = wid & 1;

    const int nwg = gridDim.x * gridDim.y;
    const int bid = blockIdx.y * gridDim.x + blockIdx.x;
    const int wgid = (bid & 7) * (nwg >> 3) + (bid >> 3);
    const int m0 = (wgid / gridDim.x) * 128;
    const int n0 = (wgid % gridDim.x) * 128;

    f32x4 acc[4][4];
    #pragma unroll
    for (int m = 0; m < 4; ++m)
        #pragma unroll
        for (int n = 0; n < 4; ++n)
            acc[m][n] = (f32x4){0.f, 0.f, 0.f, 0.f};

    const int kq = (lane >> 4) * 8;
    const int lr = lane & 15;
    const int srow = tid >> 3;
    const int scolb = (tid & 7) * 16;

    for (int k0 = 0; k0 < K; k0 += 64) {
        #pragma unroll
        for (int r = 0; r < 4; ++r) {
            int row = r * 32 + srow;
            int gcolb = scolb ^ ((row & 7) << 4);
            int lofs = row * 64 + (scolb >> 1);
            stage16(A + (size_t)(m0 + row) * lda + k0 + (gcolb >> 1), As + lofs);
            stage16(W + (size_t)(n0 + row) * ldw + k0 + (gcolb >> 1), Ws + lofs);
        }
        __syncthreads();

        #pragma unroll
        for (int sub = 0; sub < 2; ++sub) {
            short8 afr[4], bfr[4];
            #pragma unroll
            for (int m = 0; m < 4; ++m) {
                int row = wr * 64 + m * 16 + lr;
                int cs = (sub * 32 + kq) ^ ((row & 7) << 3);
                afr[m] = *(const short8*)(As + row * 64 + cs);
            }
            #pragma unroll
            for (int n = 0; n < 4; ++n) {
                int row = wc * 64 + n * 16 + lr;
                int cs = (sub * 32 + kq) ^ ((row & 7) << 3);
                bfr[n] = *(const short8*)(Ws + row * 64 + cs);
            }
            #pragma unroll
            for (int m = 0; m < 4; ++m)
                #pragma unroll
                for (int n = 0; n < 4; ++n)
                    acc[m][n] = __builtin_amdgcn_mfma_f32_16x16x32_bf16(
                        afr[m], bfr[n], acc[m][n], 0, 0, 0);
        }
        __syncthreads();
    }

    #pragma unroll
    for (int m = 0; m < 4; ++m) {
        #pragma unroll
        for (int n = 0; n < 4; ++n) {
            int colg = n0 + wc * 64 + n * 16 + (lane & 15);
            if (NMASK && colg >= Nreal) continue;
            #pragma unroll
            for (int r = 0; r < 4; ++r) {
                int rowg = m0 + wr * 64 + m * 16 + (lane >> 4) * 4 + r;
                float v = acc[m][n][r];
                if (EPI == 2) v = softplusf(v + bias[rowg]);
                storeC(&C[(size_t)rowg * ldc + colg], v);
            }
        }
    }
}

// ---------------------------------------------------------------------------
// Reduce 4 dbc partials -> dbc fp32 [M][80] + dbc48 bf16 [M][64] (pad 0)
// ---------------------------------------------------------------------------
__global__ __launch_bounds__(256) void pack48red_k(
    const float* __restrict__ part,
    float* __restrict__ dbc_f, float* __restrict__ dbc_b,
    ushortT* __restrict__ dbc48_f, ushortT* __restrict__ dbc48_b)
{
    const long n = (long)M_ * 80;
    for (long i = blockIdx.x * 256L + threadIdx.x; i < 2 * n; i += (long)gridDim.x * 256) {
        int dir = (i >= n);
        long j = dir ? i - n : i;
        int col = (int)(j % 80);
        long m = j / 80;
        size_t base = ((size_t)dir * 4 * M_ + m) * 80 + col;
        float sum = part[base] + part[base + (size_t)M_ * 80]
                  + part[base + (size_t)2 * M_ * 80] + part[base + (size_t)3 * M_ * 80];
        (dir ? dbc_b : dbc_f)[m * 80 + col] = sum;
        if (col < 64)
            (dir ? dbc48_b : dbc48_f)[m * 64 + col] = (col < 48) ? f2bf(sum) : (ushortT)0;
    }
}

// ---------------------------------------------------------------------------
// Fused depthwise conv (K=4) + bias + SiLU, emitting BOTH layouts.
// ---------------------------------------------------------------------------
__global__ __launch_bounds__(256) void conv_fused_k(
    const ushortT* __restrict__ xc_f, const ushortT* __restrict__ xc_b,
    const float* __restrict__ cwf, const float* __restrict__ cwb,
    const float* __restrict__ cbf, const float* __restrict__ cbb,
    ushortT* __restrict__ xcvcat,
    ushortT* __restrict__ xcvt_f, ushortT* __restrict__ xcvt_b)
{
    const int dir = blockIdx.z;
    const ushortT* xc = dir ? xc_b : xc_f;
    const float* cw = dir ? cwb : cwf;
    const float* cb = dir ? cbb : cbf;
    ushortT* xcvt = dir ? xcvt_b : xcvt_f;
    const int dirOff = dir * DI_;

    const int tid = threadIdx.x;
    const int m0 = blockIdx.x * 64;
    const int d0 = blockIdx.y * 64;
    const int b = m0 / L_;
    const int t0 = m0 % L_;
    const int dd = tid & 63;
    const int qr = tid >> 6;

    __shared__ ushortT xt[68][66];
    __shared__ ushortT ot[64][66];

    const int tbase = t0 + (dir ? 0 : -3);
    #pragma unroll 4
    for (int it = 0; it < 17; ++it) {
        int r = it * 4 + qr;
        if (r < 68) {
            int tr = tbase + r;
            ushortT v = 0;
            if (r < 67 && tr >= 0 && tr < L_)
                v = xc[((size_t)b * L_ + tr) * DI_ + d0 + dd];
            xt[r][dd] = v;
        }
    }
    __syncthreads();

    float cwv[4];
    #pragma unroll
    for (int q = 0; q < 4; ++q)
        cwv[q] = dir ? cw[(d0 + dd) * 4 + 3 - q] : cw[(d0 + dd) * 4 + q];
    const float cbv = cb[d0 + dd];

    #pragma unroll 4
    for (int it = 0; it < 16; ++it) {
        int tt = it * 4 + qr;
        float acc = cbv;
        #pragma unroll
        for (int q = 0; q < 4; ++q)
            acc += cwv[q] * bf2f(xt[tt + q][dd]);
        ushortT r16 = f2bf(siluf(acc));
        xcvcat[(size_t)(m0 + tt) * 3072 + dirOff + d0 + dd] = r16;
        ot[tt][dd] = r16;
    }
    __syncthreads();

    #pragma unroll 4
    for (int it = 0; it < 16; ++it) {
        int rr = it * 4 + qr;
        int cc = dd;
        xcvt[(size_t)(d0 + rr) * M_ + m0 + cc] = ot[cc][rr];
    }
}

// ---------------------------------------------------------------------------
// Scan pass 1: lane-pair split — thread owns 8 of the 16 states.
// ---------------------------------------------------------------------------
template<int DIR>
__device__ __forceinline__ void scan1_body(
    const ushortT* __restrict__ xcv_t, const ushortT* __restrict__ dt_t,
    const float* __restrict__ dbc, const float* __restrict__ Alog,
    float* __restrict__ aprod, float* __restrict__ hloc,
    float (*Bs)[16], int c, int b, int d, int half, int tid)
{
    const int t0 = c * CL_;
    #pragma unroll
    for (int it = 0; it < CL_ / 16; ++it) {
        int row = it * 16 + (tid >> 4);
        int col = tid & 15;
        int tau = t0 + row;
        int pos = DIR ? (L_ - 1 - tau) : tau;
        Bs[row][col] = dbc[((size_t)b * L_ + pos) * 80 + R_ + col];
    }
    __syncthreads();

    float A2[8];
    #pragma unroll
    for (int s = 0; s < 8; ++s)
        A2[s] = -__expf(Alog[d * S_ + half * 8 + s]) * KSC_;

    const size_t sbase = (size_t)d * M_ + b * L_;
    float h[8];
    #pragma unroll
    for (int s = 0; s < 8; ++s) h[s] = 0.f;
    float sdt = 0.f;

    for (int g = 0; g < CL_ / 32; ++g) {
        const int t0g = t0 + 32 * g;
        const int tb = DIR ? (L_ - 32 - t0g) : t0g;
        const ushortT* dp = dt_t + sbase + tb;
        const ushortT* xp = xcv_t + sbase + tb;
        short8 d8[4], x8[4];
        #pragma unroll
        for (int v = 0; v < 4; ++v) {
            d8[v] = *(const short8*)(dp + v * 8);
            x8[v] = *(const short8*)(xp + v * 8);
        }
        #pragma unroll
        for (int jj = 0; jj < 32; ++jj) {
            const int q = DIR ? (31 - jj) : jj;
            float dtv = bf2f((ushortT)d8[q >> 3][q & 7]);
            float xv  = bf2f((ushortT)x8[q >> 3][q & 7]);
            float bx = dtv * xv;
            sdt += dtv;
            const int row = 32 * g + jj;
            const f32x4* B4 = (const f32x4*)&Bs[row][0];
            #pragma unroll
            for (int qq = 0; qq < 2; ++qq) {
                f32x4 Bq = B4[half * 2 + qq];
                #pragma unroll
                for (int e2 = 0; e2 < 4; ++e2) {
                    int s = qq * 4 + e2;
                    float a = EXP2F(dtv * A2[s]);
                    h[s] = a * h[s] + bx * Bq[e2];
                }
            }
        }
    }
    size_t idx = ((((size_t)DIR * B_ + b) * NC_ + c) * DI_ + d) * S_ + half * 8;
    #pragma unroll
    for (int qv = 0; qv < 2; ++qv) {
        f32x4 ap, hl;
        #pragma unroll
        for (int e = 0; e < 4; ++e) {
            ap[e] = EXP2F(A2[qv * 4 + e] * sdt);
            hl[e] = h[qv * 4 + e];
        }
        *(f32x4*)(aprod + idx + qv * 4) = ap;
        *(f32x4*)(hloc  + idx + qv * 4) = hl;
    }
}

__global__ __launch_bounds__(256) void scan1_k(
    const ushortT* __restrict__ xcvt_f, const ushortT* __restrict__ dtt_f,
    const float* __restrict__ dbc_f, const float* __restrict__ Af,
    const ushortT* __restrict__ xcvt_b, const ushortT* __restrict__ dtt_b,
    const float* __restrict__ dbc_b, const float* __restrict__ Ab,
    float* __restrict__ aprod, float* __restrict__ hloc)
{
    __shared__ float Bs[CL_][16];
    const int dir = blockIdx.z / NC_, c = blockIdx.z % NC_;
    const int d = blockIdx.x * 128 + (threadIdx.x >> 1);
    const int half = threadIdx.x & 1;
    const int b = blockIdx.y;
    if (dir == 0)
        scan1_body<0>(xcvt_f, dtt_f, dbc_f, Af, aprod, hloc, Bs, c, b, d, half, threadIdx.x);
    else
        scan1_body<1>(xcvt_b, dtt_b, dbc_b, Ab, aprod, hloc, Bs, c, b, d, half, threadIdx.x);
}

__global__ __launch_bounds__(256) void scan2_k(
    float* __restrict__ aprod, const float* __restrict__ hloc)
{
    int q = blockIdx.x * 256 + threadIdx.x;
    if (q >= 2 * B_ * DI_ * S_) return;
    int s = q & 15;
    int t = q >> 4;
    int d = t % DI_;
    int t2 = t / DI_;
    int b = t2 & 1, dir = t2 >> 1;
    float h = 0.f;
    for (int c = 0; c < NC_; ++c) {
        size_t idx = ((((size_t)dir * B_ + b) * NC_ + c) * DI_ + d) * S_ + s;
        float a = aprod[idx], hl = hloc[idx];
        aprod[idx] = h;
        h = hl + a * h;
    }
}

// ---------------------------------------------------------------------------
// Scan pass 3 + FUSED GATE (LDS-staged): per step compute y, pre-gate with
// xv*Dp, pack into LDS ys[128d][64t]; epilogue transposes in LDS and writes
// ys * silu(z) into xcvcat with coalesced loads/stores on both sides.
// ---------------------------------------------------------------------------
template<int DIR>
__device__ __forceinline__ void scan3_body(
    const ushortT* __restrict__ xcv_t, const ushortT* __restrict__ dt_t,
    const float* __restrict__ dbc, const float* __restrict__ Alog,
    const ushortT* __restrict__ zp, const float* __restrict__ Dp,
    ushortT* __restrict__ xcvcat, const float* __restrict__ hin,
    float (*Bs)[16], float (*Cs)[16], ushortT (*ys)[66],
    int c, int b, int d0blk, int d, int half, int tid)
{
    const int t0 = c * CL_;
    #pragma unroll
    for (int it = 0; it < CL_ / 16; ++it) {
        int row = it * 16 + (tid >> 4);
        int col = tid & 15;
        int tau = t0 + row;
        int pos = DIR ? (L_ - 1 - tau) : tau;
        size_t base = ((size_t)b * L_ + pos) * 80 + R_;
        Bs[row][col] = dbc[base + col];
        Cs[row][col] = dbc[base + 16 + col];
    }
    __syncthreads();

    float A2[8];
    #pragma unroll
    for (int s = 0; s < 8; ++s)
        A2[s] = -__expf(Alog[d * S_ + half * 8 + s]) * KSC_;
    const float Dpv = Dp[d];

    size_t idx = ((((size_t)DIR * B_ + b) * NC_ + c) * DI_ + d) * S_ + half * 8;
    float h[8];
    #pragma unroll
    for (int qv = 0; qv < 2; ++qv) {
        f32x4 hv = *(const f32x4*)(hin + idx + qv * 4);
        h[qv * 4 + 0] = hv[0]; h[qv * 4 + 1] = hv[1];
        h[qv * 4 + 2] = hv[2]; h[qv * 4 + 3] = hv[3];
    }

    const size_t sbase = (size_t)d * M_ + b * L_;
    const int dloc = tid >> 1;
    union { ushortT u[4]; unsigned long long v; } pk;

    for (int g = 0; g < CL_ / 32; ++g) {
        const int t0g = t0 + 32 * g;
        const int tb = DIR ? (L_ - 32 - t0g) : t0g;
        const ushortT* dp = dt_t + sbase + tb;
        const ushortT* xp = xcv_t + sbase + tb;
        short8 d8[4], x8[4];
        #pragma unroll
        for (int v = 0; v < 4; ++v) {
            d8[v] = *(const short8*)(dp + v * 8);
            x8[v] = *(const short8*)(xp + v * 8);
        }
        #pragma unroll
        for (int jj = 0; jj < 32; ++jj) {
            const int q = DIR ? (31 - jj) : jj;
            float dtv = bf2f((ushortT)d8[q >> 3][q & 7]);
            float xv  = bf2f((ushortT)x8[q >> 3][q & 7]);
            float bx = dtv * xv;
            const int row = 32 * g + jj;
            const f32x4* B4 = (const f32x4*)&Bs[row][0];
            const f32x4* C4 = (const f32x4*)&Cs[row][0];
            float y = 0.f;
            #pragma unroll
            for (int qq = 0; qq < 2; ++qq) {
                f32x4 Bq = B4[half * 2 + qq];
                f32x4 Cq = C4[half * 2 + qq];
                #pragma unroll
                for (int e2 = 0; e2 < 4; ++e2) {
                    int s = qq * 4 + e2;
                    float a = EXP2F(dtv * A2[s]);
                    h[s] = a * h[s] + bx * Bq[e2];
                    y += h[s] * Cq[e2];
                }
            }
            y += __shfl_xor(y, 1);            // combine the two halves
            pk.u[DIR ? (3 - (jj & 3)) : (jj & 3)] = f2bf(y + xv * Dpv);
            if ((jj & 3) == 3 && half == 0) {
                int tl = DIR ? (63 - 32 * g - jj) : (32 * g + jj - 3);
                *(unsigned long long*)&ys[dloc][tl] = pk.v;
            }
        }
    }
    __syncthreads();

    // epilogue: gated coalesced write. tile rows = mbase..mbase+63 (ascending)
    const size_t mbase = (size_t)b * L_ + (DIR ? (L_ - CL_ - t0) : t0);
    const int dl2 = tid & 127;
    const int tr0 = tid >> 7;
    #pragma unroll 8
    for (int pass = 0; pass < 32; ++pass) {
        int tt = pass * 2 + tr0;
        float yg = bf2f(ys[dl2][tt]);
        float zv = bf2f(zp[(mbase + tt) * DI_ + d0blk + dl2]);
        xcvcat[(mbase + tt) * 3072 + DIR * DI_ + d0blk + dl2] = f2bf(yg * siluf(zv));
    }
}

__global__ __launch_bounds__(256) void scan3_k(
    const ushortT* __restrict__ xcvt_f, const ushortT* __restrict__ dtt_f,
    const float* __restrict__ dbc_f, const float* __restrict__ Af,
    const ushortT* __restrict__ z_f, const float* __restrict__ Dp_f,
    const ushortT* __restrict__ xcvt_b, const ushortT* __restrict__ dtt_b,
    const float* __restrict__ dbc_b, const float* __restrict__ Ab,
    const ushortT* __restrict__ z_b, const float* __restrict__ Dp_b,
    ushortT* __restrict__ xcvcat, const float* __restrict__ hin)
{
    __shared__ float Bs[CL_][16];
    __shared__ float Cs[CL_][16];
    __shared__ ushortT ys[128][66];
    const int dir = blockIdx.z / NC_, c = blockIdx.z % NC_;
    const int d0blk = blockIdx.x * 128;
    const int d = d0blk + (threadIdx.x >> 1);
    const int half = threadIdx.x & 1;
    const int b = blockIdx.y;
    if (dir == 0)
        scan3_body<0>(xcvt_f, dtt_f, dbc_f, Af, z_f, Dp_f, xcvcat, hin,
                      Bs, Cs, ys, c, b, d0blk, d, half, threadIdx.x);
    else
        scan3_body<1>(xcvt_b, dtt_b, dbc_b, Ab, z_b, Dp_b, xcvcat, hin,
                      Bs, Cs, ys, c, b, d0blk, d, half, threadIdx.x);
}

// ---------------------------------------------------------------------------
// h = x + sum(bf16 acc0..acc3) + proj_b ; LayerNorm over D=768
// ---------------------------------------------------------------------------
__global__ __launch_bounds__(256) void final_ln_k(
    const float* __restrict__ x, const ushortT* __restrict__ acc0,
    const ushortT* __restrict__ acc1, const ushortT* __restrict__ acc2,
    const ushortT* __restrict__ acc3,
    const float* __restrict__ proj_b, const float* __restrict__ ln_g,
    const float* __restrict__ ln_b, float* __restrict__ out)
{
    const int row = blockIdx.x;
    const size_t base = (size_t)row * D_;
    __shared__ float hbuf[D_];
    __shared__ float wsum[4], wsum2[4];
    float s1 = 0.f, s2 = 0.f;
    for (int n = threadIdx.x; n < D_; n += 256) {
        float h = x[base + n] + bf2f(acc0[base + n]) + bf2f(acc1[base + n])
                + bf2f(acc2[base + n]) + bf2f(acc3[base + n]) + proj_b[n];
        hbuf[n] = h;
        s1 += h; s2 += h * h;
    }
    #pragma unroll
    for (int off = 32; off; off >>= 1) {
        s1 += __shfl_down(s1, off);
        s2 += __shfl_down(s2, off);
    }
    const int wid = threadIdx.x >> 6;
    if ((threadIdx.x & 63) == 0) { wsum[wid] = s1; wsum2[wid] = s2; }
    __syncthreads();
    if (threadIdx.x == 0) {
        float t1 = wsum[0] + wsum[1] + wsum[2] + wsum[3];
        float t2 = wsum2[0] + wsum2[1] + wsum2[2] + wsum2[3];
        float mu = t1 / D_;
        wsum[0] = mu;
        wsum2[0] = t2 / D_ - mu * mu;
    }
    __syncthreads();
    const float mu = wsum[0];
    const float inv = rsqrtf(wsum2[0] + 1e-5f);
    for (int n = threadIdx.x; n < D_; n += 256) {
        out[base + n] = (hbuf[n] - mu) * inv * ln_g[n] + ln_b[n];
    }
}

// ---------------------------------------------------------------------------
extern "C" void kernel_launch(void* const* d_in, const int* in_sizes, int n_in,
                              void* d_out, int out_size, void* d_ws, size_t ws_size,
                              hipStream_t stream)
{
    const float* x        = (const float*)d_in[0];
    const float* f_in_w   = (const float*)d_in[1];
    const float* f_conv_w = (const float*)d_in[2];
    const float* f_conv_b = (const float*)d_in[3];
    const float* f_xproj  = (const float*)d_in[4];
    const float* f_dt_w   = (const float*)d_in[5];
    const float* f_dt_bv  = (const float*)d_in[6];
    const float* f_A_log  = (const float*)d_in[7];
    const float* f_Dp     = (const float*)d_in[8];
    const float* f_out_w  = (const float*)d_in[9];
    const float* b_in_w   = (const float*)d_in[10];
    const float* b_conv_w = (const float*)d_in[11];
    const float* b_conv_b = (const float*)d_in[12];
    const float* b_xproj  = (const float*)d_in[13];
    const float* b_dt_w   = (const float*)d_in[14];
    const float* b_dt_bv  = (const float*)d_in[15];
    const float* b_A_log  = (const float*)d_in[16];
    const float* b_Dp     = (const float*)d_in[17];
    const float* b_out_w  = (const float*)d_in[18];
    const float* proj_w   = (const float*)d_in[19];
    const float* proj_b   = (const float*)d_in[20];
    const float* ln_g     = (const float*)d_in[21];
    const float* ln_b     = (const float*)d_in[22];
    float* out = (float*)d_out;

    // ---- workspace layout (float units) ----
    const size_t TOKH = (size_t)M_ * DI_ / 2;
    float* p = (float*)d_ws;
    ushortT* xbf       = (ushortT*)p;  p += (size_t)M_ * D_ / 2;
    ushortT* projwbf   = (ushortT*)p;  p += (size_t)D_ * DI_ / 2;
    ushortT* inwbf_f   = (ushortT*)p;  p += (size_t)2 * DI_ * D_ / 2;   // later: Wccat
    ushortT* inwbf_b   = (ushortT*)p;  p += (size_t)2 * DI_ * D_ / 2;   // later: outwT f+b
    ushortT* xprojbf_f = (ushortT*)p;  p += (size_t)128 * DI_ / 2;
    ushortT* xprojbf_b = (ushortT*)p;  p += (size_t)128 * DI_ / 2;
    ushortT* dtw_f     = (ushortT*)p;  p += (size_t)DI_ * 64 / 2;
    ushortT* dtw_b     = (ushortT*)p;  p += (size_t)DI_ * 64 / 2;
    ushortT* xc_f      = (ushortT*)p;  p += TOKH;
    ushortT* z_f       = (ushortT*)p;  p += TOKH;
    ushortT* xc_b      = (ushortT*)p;  p += TOKH;
    ushortT* z_b       = (ushortT*)p;  p += TOKH;
    ushortT* xcvcat    = (ushortT*)p;  p += (size_t)M_ * 3072 / 2;
    ushortT* xcvt_f    = (ushortT*)p;  p += TOKH;
    ushortT* xcvt_b    = (ushortT*)p;  p += TOKH;
    ushortT* dtt_f     = (ushortT*)p;  p += TOKH;
    ushortT* dtt_b     = (ushortT*)p;  p += TOKH;
    float*   dbc_f     = p;            p += (size_t)M_ * 80;
    float*   dbc_b     = p;            p += (size_t)M_ * 80;
    ushortT* dbc48_f   = (ushortT*)p;  p += (size_t)M_ * 64 / 2;
    ushortT* dbc48_b   = (ushortT*)p;  p += (size_t)M_ * 64 / 2;
    float*   aprod     = p;            p += (size_t)2 * B_ * NC_ * DI_ * S_;
    float*   hloc      = p;            p += (size_t)2 * B_ * NC_ * DI_ * S_;
    // aliases (dead-before-reuse, stream-ordered):
    ushortT* Wccat   = inwbf_f;            // [768][3072]
    ushortT* outwT_f = inwbf_b;            // [1536][768]
    ushortT* outwT_b = inwbf_b + (size_t)DI_ * D_;
    float*   dbc_part = aprod;             // [8][M][80]
    // bf16 split-K x4 partials (dead buffers; each needs M*D bf16 = 6.3 MB):
    ushortT* accb0  = (ushortT*)aprod;
    ushortT* accb1  = (ushortT*)hloc;
    ushortT* accb2  = (ushortT*)xcvt_f;
    ushortT* accb3  = (ushortT*)xcvt_b;

    dim3 blk(256);

    // ---- 1) mega-convert fp32 -> bf16 ----
    Segs8 segs;
    segs.s[0] = { x,        xbf,       (long)M_ * D_,      1, 1 };
    segs.s[1] = { proj_w,   projwbf,   (long)D_ * DI_,     1, 1 };
    segs.s[2] = { f_xproj,  xprojbf_f, (long)80 * DI_,     1, 1 };
    segs.s[3] = { b_xproj,  xprojbf_b, (long)80 * DI_,     1, 1 };
    segs.s[4] = { f_dt_w,   dtw_f,     (long)DI_ * 64,    48, 64 };
    segs.s[5] = { b_dt_w,   dtw_b,     (long)DI_ * 64,    48, 64 };
    segs.s[6] = { f_in_w,   inwbf_f,   (long)2 * DI_ * D_, 1, 1 };
    segs.s[7] = { b_in_w,   inwbf_b,   (long)2 * DI_ * D_, 1, 1 };
    convert_all_k<<<1024, blk, 0, stream>>>(segs);

    // ---- 2) xz GEMM (4 halves), BK=64 + swizzle + XCD remap ----
    P8 px = {};
    px.A[0] = px.A[1] = px.A[2] = px.A[3] = xbf;
    px.W[0] = inwbf_f; px.W[1] = inwbf_f + (size_t)DI_ * D_;
    px.W[2] = inwbf_b; px.W[3] = inwbf_b + (size_t)DI_ * D_;
    px.C[0] = xc_f; px.C[1] = z_f; px.C[2] = xc_b; px.C[3] = z_b;
    mfma64<ushortT, 0, false><<<dim3(12, 32, 4), blk, 0, stream>>>(
        px, D_, D_, DI_, D_, 0);

    // ---- 3) out_w transpose-convert ----
    transconv_k<<<dim3(24, 12, 2), blk, 0, stream>>>(f_out_w, b_out_w, outwT_f, outwT_b);

    // ---- 4) Wc = proj_slice @ out_w -> Wccat [768][3072] ----
    P8 pc = {};
    pc.A[0] = projwbf;       pc.A[1] = projwbf + D_;
    pc.W[0] = outwT_f;       pc.W[1] = outwT_b;
    pc.C[0] = Wccat;         pc.C[1] = Wccat + DI_;
    mfma64<ushortT, 0, false><<<dim3(12, 6, 2), blk, 0, stream>>>(
        pc, 2 * D_, D_, 3072, D_, 0);

    // ---- 5) conv + SiLU, both layouts ----
    conv_fused_k<<<dim3(M_ / 64, DI_ / 64, 2), blk, 0, stream>>>(
        xc_f, xc_b, f_conv_w, b_conv_w, f_conv_b, b_conv_b,
        xcvcat, xcvt_f, xcvt_b);

    // ---- 6) dbc split-K GEMM (8 z-slices) -> partials ----
    P8 pd = {};
    for (int z = 0; z < 8; ++z) {
        int dir = z >> 2, ks = z & 3;
        pd.A[z] = xcvcat + dir * DI_ + ks * 384;
        pd.W[z] = (dir ? xprojbf_b : xprojbf_f) + ks * 384;
        pd.C[z] = dbc_part + (size_t)z * M_ * 80;
    }
    mfma64<float, 0, true><<<dim3(1, 32, 8), blk, 0, stream>>>(
        pd, 3072, DI_, 80, 384, 80);

    // ---- 7) reduce partials -> dbc fp32 + dbc48 bf16 ----
    pack48red_k<<<1024, blk, 0, stream>>>(dbc_part, dbc_f, dbc_b, dbc48_f, dbc48_b);

    // ---- 8) dtt[d][m] = softplus(dtw @ dbc48^T + dt_b[d]) ----
    P8 pt = {};
    pt.A[0] = dtw_f;   pt.A[1] = dtw_b;
    pt.W[0] = dbc48_f; pt.W[1] = dbc48_b;
    pt.C[0] = dtt_f;   pt.C[1] = dtt_b;
    pt.bias[0] = f_dt_bv; pt.bias[1] = b_dt_bv;
    mfma64<ushortT, 2, false><<<dim3(32, 12, 2), blk, 0, stream>>>(
        pt, 64, 64, M_, 64, 0);

    // ---- 9) chunked selective scan; scan3 fuses gate via LDS staging ----
    scan1_k<<<dim3(DI_ / 128, B_, 2 * NC_), blk, 0, stream>>>(
        xcvt_f, dtt_f, dbc_f, f_A_log, xcvt_b, dtt_b, dbc_b, b_A_log, aprod, hloc);
    scan2_k<<<(2 * B_ * DI_ * S_ + 255) / 256, blk, 0, stream>>>(aprod, hloc);
    scan3_k<<<dim3(DI_ / 128, B_, 2 * NC_), blk, 0, stream>>>(
        xcvt_f, dtt_f, dbc_f, f_A_log, z_f, f_Dp,
        xcvt_b, dtt_b, dbc_b, b_A_log, z_b, b_Dp,
        xcvcat, aprod);

    // ---- 10) accb = yp_cat @ Wccat^T, split-K x4, bf16 partials ----
    P8 pf = {};
    pf.A[0] = xcvcat;              pf.W[0] = Wccat;              pf.C[0] = accb0;
    pf.A[1] = xcvcat + 768;        pf.W[1] = Wccat + 768;        pf.C[1] = accb1;
    pf.A[2] = xcvcat + 2 * 768;    pf.W[2] = Wccat + 2 * 768;    pf.C[2] = accb2;
    pf.A[3] = xcvcat + 3 * 768;    pf.W[3] = Wccat + 3 * 768;    pf.C[3] = accb3;
    mfma64<ushortT, 0, false><<<dim3(6, 32, 4), blk, 0, stream>>>(
        pf, 3072, 3072, D_, 768, 0);

    // ---- 11) residual + LayerNorm ----
    final_ln_k<<<M_, blk, 0, stream>>>(x, accb0, accb1, accb2, accb3,
                                       proj_b, ln_g, ln_b, out);
}